// Round 1
// baseline (1140.679 us; speedup 1.0000x reference)
//
#include <hip/hip_runtime.h>
#include <cstdint>
#include <cstddef>

#define BB 2
#define NN 8192
#define EE 131072
#define FFdim 128
#define HHdim 256
#define NHEAD 4
#define DHEAD 64
#define FEATD 268
#define LDF 272          // edge LDS row stride (floats)
#define LDN 388          // node LDS row stride (floats)
#define TE 64            // edges (or rows) per block

__device__ __forceinline__ float silu_f(float x) {
    return x / (1.0f + __expf(-x));
}

// ---- 8x8 register-tile GEMM: 8 LDS rows (lA, stride ldA) x 8 weight cols ----
// weight row k at wB + k*ldB, 8 consecutive columns starting at wB.
template <int NK4>
__device__ __forceinline__ void gemm8x8(const float* __restrict__ lA, int ldA,
                                        const float* __restrict__ wB, int ldB,
                                        float (&acc)[8][8]) {
#pragma unroll 2
    for (int k4 = 0; k4 < NK4; ++k4) {
        const int kk = k4 * 4;
        float a4[8][4];
#pragma unroll
        for (int e = 0; e < 8; ++e) {
            float4 v = *(const float4*)(lA + e * ldA + kk);
            a4[e][0] = v.x; a4[e][1] = v.y; a4[e][2] = v.z; a4[e][3] = v.w;
        }
#pragma unroll
        for (int f = 0; f < 4; ++f) {
            const float* wr = wB + (size_t)(kk + f) * ldB;
            float4 w0 = *(const float4*)(wr);
            float4 w1v = *(const float4*)(wr + 4);
#pragma unroll
            for (int e = 0; e < 8; ++e) {
                float av = a4[e][f];
                acc[e][0] += av * w0.x;  acc[e][1] += av * w0.y;
                acc[e][2] += av * w0.z;  acc[e][3] += av * w0.w;
                acc[e][4] += av * w1v.x; acc[e][5] += av * w1v.y;
                acc[e][6] += av * w1v.z; acc[e][7] += av * w1v.w;
            }
        }
    }
}

template <int NK4>
__device__ __forceinline__ void gemm8x4(const float* __restrict__ lA, int ldA,
                                        const float* __restrict__ wB, int ldB,
                                        float (&acc)[8][4]) {
#pragma unroll 2
    for (int k4 = 0; k4 < NK4; ++k4) {
        const int kk = k4 * 4;
        float a4[8][4];
#pragma unroll
        for (int e = 0; e < 8; ++e) {
            float4 v = *(const float4*)(lA + e * ldA + kk);
            a4[e][0] = v.x; a4[e][1] = v.y; a4[e][2] = v.z; a4[e][3] = v.w;
        }
#pragma unroll
        for (int f = 0; f < 4; ++f) {
            const float* wr = wB + (size_t)(kk + f) * ldB;
            float4 w0 = *(const float4*)(wr);
#pragma unroll
            for (int e = 0; e < 8; ++e) {
                float av = a4[e][f];
                acc[e][0] += av * w0.x; acc[e][1] += av * w0.y;
                acc[e][2] += av * w0.z; acc[e][3] += av * w0.w;
            }
        }
    }
}

// ---------------------------------------------------------------------------
// init: zero agg workspace (B*N*H floats) and seed coord_out with coord.
// grid: 4096 x 256 => 1,048,576 threads == B*N*H/4 float4s exactly.
__global__ void init_kernel(float4* __restrict__ agg4,
                            float* __restrict__ coord_out,
                            const float* __restrict__ coord) {
    int i = blockIdx.x * blockDim.x + threadIdx.x;
    agg4[i] = make_float4(0.f, 0.f, 0.f, 0.f);
    if (i < BB * NN * 3) coord_out[i] = coord[i];
}

// ---------------------------------------------------------------------------
// edge kernel: one block = 64 edges of one batch. 256 threads.
__global__ __launch_bounds__(256, 2)
void edge_kernel(const float* __restrict__ h,
                 const float* __restrict__ coord,
                 const int* __restrict__ eidx,
                 const float* __restrict__ w1, const float* __restrict__ b1,
                 const float* __restrict__ w2, const float* __restrict__ b2,
                 const float* __restrict__ lng, const float* __restrict__ lnb,
                 const float* __restrict__ cw1, const float* __restrict__ cb1,
                 const float* __restrict__ cw2,
                 float* __restrict__ agg, float* __restrict__ coord_out) {
    __shared__ float buf[TE * LDF];      // feat -> hmid -> edge_feat (stride LDF)
    __shared__ int row_s[TE], col_s[TE];
    __shared__ float cd_s[TE][3];
    __shared__ float w_s[TE];

    const int tid = threadIdx.x;
    const int b = blockIdx.y;
    const int e0 = blockIdx.x * TE;
    const int jg = tid & 31, eg = tid >> 5;
    const int j0 = jg * 8, et = eg * 8;
    const int hh = j0 >> 6;       // head for GEMM1/GEMM2 columns
    const int d0 = j0 & 63;

    // --- phase 1: indices + geometric features (one thread per edge) ---
    if (tid < TE) {
        const int e = e0 + tid;
        const int r = eidx[e], c = eidx[EE + e];
        row_s[tid] = r; col_s[tid] = c;
        const float* pi = coord + ((size_t)b * NN + r) * 3;
        const float* pk = coord + ((size_t)b * NN + c) * 3;
        float ci0 = pi[0], ci1 = pi[1], ci2 = pi[2];
        float ck0 = pk[0], ck1 = pk[1], ck2 = pk[2];
        float dx = ci0 - ck0, dy = ci1 - ck1, dz = ci2 - ck2;
        float radial = dx * dx + dy * dy + dz * dz;
        float dist = sqrtf(radial);
        float dotv = ci0 * ck0 + ci1 * ck1 + ci2 * ck2;
        float inva = 1.0f / (dist + 1e-8f);
        float a0 = dx * inva, a1 = dy * inva, a2 = dz * inva;
        float cr0 = ci1 * ck2 - ci2 * ck1;
        float cr1 = ci2 * ck0 - ci0 * ck2;
        float cr2 = ci0 * ck1 - ci1 * ck0;
        float nb = sqrtf(cr0 * cr0 + cr1 * cr1 + cr2 * cr2);
        float invb = 1.0f / (nb + 1e-8f);
        float b0 = cr0 * invb, b1v = cr1 * invb, b2v = cr2 * invb;
        float c0 = a1 * b2v - a2 * b1v;
        float c1 = a2 * b0 - a0 * b2v;
        float c2 = a0 * b1v - a1 * b0;
        float na = sqrtf(a0 * a0 + a1 * a1 + a2 * a2);
        float nbn = sqrtf(b0 * b0 + b1v * b1v + b2v * b2v);
        float nc = sqrtf(c0 * c0 + c1 * c1 + c2 * c2);
        bool bad = (na < 1e-6f) || (nbn < 1e-6f) || (nc < 1e-6f);
        float s[9];
        if (bad) {
            s[0] = 1.f; s[1] = 0.f; s[2] = 0.f;
            s[3] = 0.f; s[4] = 1.f; s[5] = 0.f;
            s[6] = 0.f; s[7] = 0.f; s[8] = 1.f;
        } else {
            s[0] = a0; s[1] = b0;  s[2] = c0;
            s[3] = a1; s[4] = b1v; s[5] = c1;
            s[6] = a2; s[7] = b2v; s[8] = c2;
        }
        float* fp = &buf[tid * LDF];
        fp[256] = radial; fp[257] = dist; fp[258] = dotv;
#pragma unroll
        for (int q = 0; q < 9; ++q) fp[259 + q] = s[q];
        cd_s[tid][0] = dx; cd_s[tid][1] = dy; cd_s[tid][2] = dz;
    }
    __syncthreads();

    // --- phase 2: gather h[row], h[col] into feat (float4) ---
    for (int idx = tid; idx < TE * 64; idx += 256) {
        const int e = idx >> 6, c4 = idx & 63;
        float4 v = (c4 < 32)
            ? *(const float4*)&h[((size_t)b * NN + row_s[e]) * FFdim + c4 * 4]
            : *(const float4*)&h[((size_t)b * NN + col_s[e]) * FFdim + (c4 - 32) * 4];
        *(float4*)&buf[e * LDF + c4 * 4] = v;
    }
    __syncthreads();

    // --- phase 3: GEMM1 (268 -> 256, per-head weights) + silu ---
    float acc[8][8];
#pragma unroll
    for (int i = 0; i < 8; ++i)
#pragma unroll
        for (int j = 0; j < 8; ++j) acc[i][j] = 0.f;
    gemm8x8<FEATD / 4>(&buf[et * LDF], LDF,
                       &w1[(size_t)hh * FEATD * DHEAD + d0], DHEAD, acc);
    float bias1[8];
#pragma unroll
    for (int jj = 0; jj < 8; ++jj) bias1[jj] = b1[hh * DHEAD + d0 + jj];
    __syncthreads();   // everyone done reading feat
#pragma unroll
    for (int e = 0; e < 8; ++e) {
        float4 o0, o1;
        o0.x = silu_f(acc[e][0] + bias1[0]); o0.y = silu_f(acc[e][1] + bias1[1]);
        o0.z = silu_f(acc[e][2] + bias1[2]); o0.w = silu_f(acc[e][3] + bias1[3]);
        o1.x = silu_f(acc[e][4] + bias1[4]); o1.y = silu_f(acc[e][5] + bias1[5]);
        o1.z = silu_f(acc[e][6] + bias1[6]); o1.w = silu_f(acc[e][7] + bias1[7]);
        *(float4*)&buf[(et + e) * LDF + j0] = o0;
        *(float4*)&buf[(et + e) * LDF + j0 + 4] = o1;
    }
    __syncthreads();

    // --- phase 4: GEMM2 (block-diagonal 64 -> 64 per head) + bias ---
#pragma unroll
    for (int i = 0; i < 8; ++i)
#pragma unroll
        for (int j = 0; j < 8; ++j) acc[i][j] = 0.f;
    gemm8x8<DHEAD / 4>(&buf[et * LDF + hh * DHEAD], LDF,
                       &w2[(size_t)hh * DHEAD * DHEAD + d0], DHEAD, acc);
    float bias2[8];
#pragma unroll
    for (int jj = 0; jj < 8; ++jj) bias2[jj] = b2[hh * DHEAD + d0 + jj];

    // --- phase 5: LayerNorm over 256 (reduce across the 32 threads of eg) ---
    float mu[8], rs[8];
#pragma unroll
    for (int e = 0; e < 8; ++e) {
        float s = 0.f, s2 = 0.f;
#pragma unroll
        for (int jj = 0; jj < 8; ++jj) {
            float x = acc[e][jj] + bias2[jj];
            acc[e][jj] = x;
            s += x; s2 += x * x;
        }
#pragma unroll
        for (int m = 1; m <= 16; m <<= 1) {
            s += __shfl_xor(s, m, 64);
            s2 += __shfl_xor(s2, m, 64);
        }
        float mean = s * (1.0f / 256.0f);
        float var = s2 * (1.0f / 256.0f) - mean * mean;
        mu[e] = mean;
        rs[e] = rsqrtf(var + 1e-5f);
    }
    float gv[8], bv[8];
#pragma unroll
    for (int jj = 0; jj < 8; ++jj) { gv[jj] = lng[j0 + jj]; bv[jj] = lnb[j0 + jj]; }
    __syncthreads();   // everyone done reading hmid
#pragma unroll
    for (int e = 0; e < 8; ++e) {
        float4 o0, o1;
        o0.x = (acc[e][0] - mu[e]) * rs[e] * gv[0] + bv[0];
        o0.y = (acc[e][1] - mu[e]) * rs[e] * gv[1] + bv[1];
        o0.z = (acc[e][2] - mu[e]) * rs[e] * gv[2] + bv[2];
        o0.w = (acc[e][3] - mu[e]) * rs[e] * gv[3] + bv[3];
        o1.x = (acc[e][4] - mu[e]) * rs[e] * gv[4] + bv[4];
        o1.y = (acc[e][5] - mu[e]) * rs[e] * gv[5] + bv[5];
        o1.z = (acc[e][6] - mu[e]) * rs[e] * gv[6] + bv[6];
        o1.w = (acc[e][7] - mu[e]) * rs[e] * gv[7] + bv[7];
        *(float4*)&buf[(et + e) * LDF + j0] = o0;
        *(float4*)&buf[(et + e) * LDF + j0 + 4] = o1;
    }
    __syncthreads();

    // --- phase 6: GEMM3 (256 -> 256) + silu + dot with coord_w2 -> w[e] ---
#pragma unroll
    for (int i = 0; i < 8; ++i)
#pragma unroll
        for (int j = 0; j < 8; ++j) acc[i][j] = 0.f;
    gemm8x8<HHdim / 4>(&buf[et * LDF], LDF, &cw1[j0], HHdim, acc);
    float cb[8], cw[8];
#pragma unroll
    for (int jj = 0; jj < 8; ++jj) { cb[jj] = cb1[j0 + jj]; cw[jj] = cw2[j0 + jj]; }
#pragma unroll
    for (int e = 0; e < 8; ++e) {
        float s = 0.f;
#pragma unroll
        for (int jj = 0; jj < 8; ++jj) {
            float t = silu_f(acc[e][jj] + cb[jj]);
            s += t * cw[jj];
        }
#pragma unroll
        for (int m = 1; m <= 16; m <<= 1) s += __shfl_xor(s, m, 64);
        if (jg == 0) w_s[et + e] = s;
    }
    __syncthreads();

    // --- phase 7: scatter: agg += edge_feat ; coord_out += coord_diff * w ---
    for (int e = 0; e < TE; ++e) {
        float v = buf[e * LDF + tid];
        atomicAdd(&agg[((size_t)b * NN + row_s[e]) * HHdim + tid], v);
    }
    if (tid < TE * 3) {
        int e = tid / 3, ax = tid % 3;
        atomicAdd(&coord_out[((size_t)b * NN + row_s[e]) * 3 + ax],
                  cd_s[e][ax] * w_s[e]);
    }
}

// ---------------------------------------------------------------------------
// node kernel: one block = 64 node-rows (flattened b*N+n). 256 threads.
__global__ __launch_bounds__(256, 1)
void node_kernel(const float* __restrict__ h,
                 const float* __restrict__ agg,
                 const float* __restrict__ nw1, const float* __restrict__ nb1,
                 const float* __restrict__ nw2, const float* __restrict__ nb2,
                 float* __restrict__ hout) {
    __shared__ float buf[TE * LDN];   // [h|agg] (384) -> mid (256)
    const int tid = threadIdx.x;
    const size_t m0 = (size_t)blockIdx.x * TE;
    const int jg = tid & 31, eg = tid >> 5;
    const int et = eg * 8;

    // stage [h, agg]
    for (int idx = tid; idx < TE * 96; idx += 256) {
        const int r = idx / 96, c4 = idx % 96;
        const size_t m = m0 + r;
        float4 v = (c4 < 32)
            ? *(const float4*)&h[m * FFdim + c4 * 4]
            : *(const float4*)&agg[m * HHdim + (c4 - 32) * 4];
        *(float4*)&buf[r * LDN + c4 * 4] = v;
    }
    __syncthreads();

    // GEMM A: 384 -> 256, silu
    const int j0 = jg * 8;
    float acc[8][8];
#pragma unroll
    for (int i = 0; i < 8; ++i)
#pragma unroll
        for (int j = 0; j < 8; ++j) acc[i][j] = 0.f;
    gemm8x8<(FFdim + HHdim) / 4>(&buf[et * LDN], LDN, &nw1[j0], HHdim, acc);
    float bias1[8];
#pragma unroll
    for (int jj = 0; jj < 8; ++jj) bias1[jj] = nb1[j0 + jj];
    __syncthreads();
#pragma unroll
    for (int e = 0; e < 8; ++e) {
        float4 o0, o1;
        o0.x = silu_f(acc[e][0] + bias1[0]); o0.y = silu_f(acc[e][1] + bias1[1]);
        o0.z = silu_f(acc[e][2] + bias1[2]); o0.w = silu_f(acc[e][3] + bias1[3]);
        o1.x = silu_f(acc[e][4] + bias1[4]); o1.y = silu_f(acc[e][5] + bias1[5]);
        o1.z = silu_f(acc[e][6] + bias1[6]); o1.w = silu_f(acc[e][7] + bias1[7]);
        *(float4*)&buf[(et + e) * LDN + j0] = o0;
        *(float4*)&buf[(et + e) * LDN + j0 + 4] = o1;
    }
    __syncthreads();

    // GEMM B: 256 -> 128, + bias + residual
    const int j0b = jg * 4;
    float accb[8][4];
#pragma unroll
    for (int i = 0; i < 8; ++i)
#pragma unroll
        for (int j = 0; j < 4; ++j) accb[i][j] = 0.f;
    gemm8x4<HHdim / 4>(&buf[et * LDN], LDN, &nw2[j0b], FFdim, accb);
    float4 bb = *(const float4*)&nb2[j0b];
#pragma unroll
    for (int e = 0; e < 8; ++e) {
        const size_t m = m0 + et + e;
        float4 hv = *(const float4*)&h[m * FFdim + j0b];
        float4 o;
        o.x = accb[e][0] + bb.x + hv.x;
        o.y = accb[e][1] + bb.y + hv.y;
        o.z = accb[e][2] + bb.z + hv.z;
        o.w = accb[e][3] + bb.w + hv.w;
        *(float4*)&hout[m * FFdim + j0b] = o;
    }
}

// ---------------------------------------------------------------------------
extern "C" void kernel_launch(void* const* d_in, const int* in_sizes, int n_in,
                              void* d_out, int out_size, void* d_ws, size_t ws_size,
                              hipStream_t stream) {
    const float* h     = (const float*)d_in[0];
    const float* coord = (const float*)d_in[1];
    const int*   eidx  = (const int*)d_in[2];
    const float* w1    = (const float*)d_in[3];
    const float* b1    = (const float*)d_in[4];
    const float* w2    = (const float*)d_in[5];
    const float* b2    = (const float*)d_in[6];
    const float* lng   = (const float*)d_in[7];
    const float* lnb   = (const float*)d_in[8];
    const float* nw1   = (const float*)d_in[9];
    const float* nb1   = (const float*)d_in[10];
    const float* nw2   = (const float*)d_in[11];
    const float* nb2   = (const float*)d_in[12];
    const float* cw1   = (const float*)d_in[13];
    const float* cb1   = (const float*)d_in[14];
    const float* cw2   = (const float*)d_in[15];

    float* hout = (float*)d_out;
    float* coord_out = hout + (size_t)BB * NN * FFdim;
    float* agg = (float*)d_ws;   // B*N*H floats = 16 MiB

    hipLaunchKernelGGL(init_kernel, dim3((BB * NN * HHdim / 4) / 256), dim3(256),
                       0, stream, (float4*)agg, coord_out, coord);
    hipLaunchKernelGGL(edge_kernel, dim3(EE / TE, BB), dim3(256), 0, stream,
                       h, coord, eidx, w1, b1, w2, b2, lng, lnb, cw1, cb1, cw2,
                       agg, coord_out);
    hipLaunchKernelGGL(node_kernel, dim3((BB * NN) / TE), dim3(256), 0, stream,
                       h, agg, nw1, nb1, nw2, nb2, hout);
}

// Round 2
// 703.154 us; speedup vs baseline: 1.6222x; 1.6222x over previous
//
#include <hip/hip_runtime.h>
#include <cstdint>
#include <cstddef>

#define BB 2
#define NN 8192
#define EE 131072
#define FFdim 128
#define HHdim 256
#define NHEAD 4
#define DHEAD 64
#define FEATD 268
#define K1PAD 288        // FEAT padded to multiple of 32
#define SF 296           // featA LDS row stride (ushort); 592B: 148dw%32=20 -> 2-way, free
#define SH 264           // hmid/ef LDS row stride (ushort); 528B: 132dw%32=4 -> 2-way, free
#define LDN 388          // node LDS row stride (floats)
#define TE 64

typedef short bf16x8 __attribute__((ext_vector_type(8)));
typedef float floatx4 __attribute__((ext_vector_type(4)));

__device__ __forceinline__ float silu_f(float x) {
    return x / (1.0f + __expf(-x));
}
__device__ __forceinline__ unsigned short f2bf(float x) {
    unsigned int u = __float_as_uint(x);
    unsigned int r = (u + 0x7fffu + ((u >> 16) & 1u)) >> 16;
    return (unsigned short)r;
}

// ---------------------------------------------------------------------------
// fp32 8x8 register-tile GEMM helpers (node kernel)
template <int NK4>
__device__ __forceinline__ void gemm8x8(const float* __restrict__ lA, int ldA,
                                        const float* __restrict__ wB, int ldB,
                                        float (&acc)[8][8]) {
#pragma unroll 2
    for (int k4 = 0; k4 < NK4; ++k4) {
        const int kk = k4 * 4;
        float a4[8][4];
#pragma unroll
        for (int e = 0; e < 8; ++e) {
            float4 v = *(const float4*)(lA + e * ldA + kk);
            a4[e][0] = v.x; a4[e][1] = v.y; a4[e][2] = v.z; a4[e][3] = v.w;
        }
#pragma unroll
        for (int f = 0; f < 4; ++f) {
            const float* wr = wB + (size_t)(kk + f) * ldB;
            float4 w0 = *(const float4*)(wr);
            float4 w1v = *(const float4*)(wr + 4);
#pragma unroll
            for (int e = 0; e < 8; ++e) {
                float av = a4[e][f];
                acc[e][0] += av * w0.x;  acc[e][1] += av * w0.y;
                acc[e][2] += av * w0.z;  acc[e][3] += av * w0.w;
                acc[e][4] += av * w1v.x; acc[e][5] += av * w1v.y;
                acc[e][6] += av * w1v.z; acc[e][7] += av * w1v.w;
            }
        }
    }
}

template <int NK4>
__device__ __forceinline__ void gemm8x4(const float* __restrict__ lA, int ldA,
                                        const float* __restrict__ wB, int ldB,
                                        float (&acc)[8][4]) {
#pragma unroll 2
    for (int k4 = 0; k4 < NK4; ++k4) {
        const int kk = k4 * 4;
        float a4[8][4];
#pragma unroll
        for (int e = 0; e < 8; ++e) {
            float4 v = *(const float4*)(lA + e * ldA + kk);
            a4[e][0] = v.x; a4[e][1] = v.y; a4[e][2] = v.z; a4[e][3] = v.w;
        }
#pragma unroll
        for (int f = 0; f < 4; ++f) {
            const float* wr = wB + (size_t)(kk + f) * ldB;
            float4 w0 = *(const float4*)(wr);
#pragma unroll
            for (int e = 0; e < 8; ++e) {
                float av = a4[e][f];
                acc[e][0] += av * w0.x; acc[e][1] += av * w0.y;
                acc[e][2] += av * w0.z; acc[e][3] += av * w0.w;
            }
        }
    }
}

// ---------------------------------------------------------------------------
// init: zero agg workspace and seed coord_out with coord.
__global__ void init_kernel(float4* __restrict__ agg4,
                            float* __restrict__ coord_out,
                            const float* __restrict__ coord) {
    int i = blockIdx.x * blockDim.x + threadIdx.x;
    agg4[i] = make_float4(0.f, 0.f, 0.f, 0.f);
    if (i < BB * NN * 3) coord_out[i] = coord[i];
}

// ---------------------------------------------------------------------------
// prep: fp32 weights -> transposed bf16 layouts in ws.
// w1T[n=0..255][k=0..287]  (n = h*64+d, zero-pad k>=268)
// w2T[n=0..255][din=0..63] (n = h*64+dout)
// cw1T[n=0..255][k=0..255]
#define W1T_ELEMS (256 * K1PAD)
#define W2T_ELEMS (256 * 64)
#define CW1T_ELEMS (256 * 256)
__global__ void prep_weights(const float* __restrict__ w1,
                             const float* __restrict__ w2,
                             const float* __restrict__ cw1,
                             unsigned short* __restrict__ w1T,
                             unsigned short* __restrict__ w2T,
                             unsigned short* __restrict__ cw1T) {
    int idx = blockIdx.x * blockDim.x + threadIdx.x;
    if (idx < W1T_ELEMS) {
        int n = idx / K1PAD, k = idx % K1PAD;
        int hh = n >> 6, d = n & 63;
        float v = (k < FEATD) ? w1[((size_t)hh * FEATD + k) * DHEAD + d] : 0.f;
        w1T[idx] = f2bf(v);
    } else if (idx < W1T_ELEMS + W2T_ELEMS) {
        int j = idx - W1T_ELEMS;
        int hh = j >> 12, dout = (j >> 6) & 63, din = j & 63;
        w2T[j] = f2bf(w2[(size_t)hh * 4096 + din * 64 + dout]);
    } else if (idx < W1T_ELEMS + W2T_ELEMS + CW1T_ELEMS) {
        int j = idx - (W1T_ELEMS + W2T_ELEMS);
        int n = j >> 8, k = j & 255;
        cw1T[j] = f2bf(cw1[k * 256 + n]);
    }
}

// ---------------------------------------------------------------------------
// edge kernel (MFMA bf16): one block = 64 edges of one batch, 256 threads.
// Wave w owns output columns [w*64, w*64+64) (= head w for GEMM1/GEMM2).
__global__ __launch_bounds__(256, 2)
void edge_kernel(const float* __restrict__ h,
                 const float* __restrict__ coord,
                 const int* __restrict__ eidx,
                 const unsigned short* __restrict__ w1T, const float* __restrict__ b1,
                 const unsigned short* __restrict__ w2T, const float* __restrict__ b2,
                 const float* __restrict__ lng, const float* __restrict__ lnb,
                 const unsigned short* __restrict__ cw1T, const float* __restrict__ cb1,
                 const float* __restrict__ cw2,
                 float* __restrict__ agg, float* __restrict__ coord_out) {
    __shared__ unsigned short bufA[TE * SF];   // feat bf16; later reused as ef bf16
    __shared__ unsigned short bufH[TE * SH];   // hmid bf16
    __shared__ int row_s[TE];
    __shared__ float cd_s[TE][3];
    __shared__ float w_s[TE];
    __shared__ float2 lnred[TE][4];
    __shared__ float mu_s[TE], rs_s[TE];
    __shared__ float wpart[TE][4];

    const int tid = threadIdx.x;
    const int b = blockIdx.y;
    const int e0 = blockIdx.x * TE;
    const int lane = tid & 63;
    const int w = tid >> 6;          // wave id = column quarter / head
    const int lm = lane & 15;        // row (A) / col (B,C) within 16-tile
    const int quad = lane >> 4;      // 0..3
    const int koff = quad * 8;

    // --- phase 1: geometry (one thread per edge) ---
    if (tid < TE) {
        const int e = e0 + tid;
        const int r = eidx[e], c = eidx[EE + e];
        row_s[tid] = r;
        const float* pi = coord + ((size_t)b * NN + r) * 3;
        const float* pk = coord + ((size_t)b * NN + c) * 3;
        float ci0 = pi[0], ci1 = pi[1], ci2 = pi[2];
        float ck0 = pk[0], ck1 = pk[1], ck2 = pk[2];
        float dx = ci0 - ck0, dy = ci1 - ck1, dz = ci2 - ck2;
        float radial = dx * dx + dy * dy + dz * dz;
        float dist = sqrtf(radial);
        float dotv = ci0 * ck0 + ci1 * ck1 + ci2 * ck2;
        float inva = 1.0f / (dist + 1e-8f);
        float a0 = dx * inva, a1 = dy * inva, a2 = dz * inva;
        float cr0 = ci1 * ck2 - ci2 * ck1;
        float cr1 = ci2 * ck0 - ci0 * ck2;
        float cr2 = ci0 * ck1 - ci1 * ck0;
        float nb = sqrtf(cr0 * cr0 + cr1 * cr1 + cr2 * cr2);
        float invb = 1.0f / (nb + 1e-8f);
        float b0 = cr0 * invb, b1v = cr1 * invb, b2v = cr2 * invb;
        float c0 = a1 * b2v - a2 * b1v;
        float c1 = a2 * b0 - a0 * b2v;
        float c2 = a0 * b1v - a1 * b0;
        float na = sqrtf(a0 * a0 + a1 * a1 + a2 * a2);
        float nbn = sqrtf(b0 * b0 + b1v * b1v + b2v * b2v);
        float nc = sqrtf(c0 * c0 + c1 * c1 + c2 * c2);
        bool bad = (na < 1e-6f) || (nbn < 1e-6f) || (nc < 1e-6f);
        float s[12];
        s[0] = radial; s[1] = dist; s[2] = dotv;
        if (bad) {
            s[3] = 1.f; s[4] = 0.f; s[5] = 0.f;
            s[6] = 0.f; s[7] = 1.f; s[8] = 0.f;
            s[9] = 0.f; s[10] = 0.f; s[11] = 1.f;
        } else {
            s[3] = a0;  s[4] = b0;  s[5] = c0;
            s[6] = a1;  s[7] = b1v; s[8] = c1;
            s[9] = a2;  s[10] = b2v; s[11] = c2;
        }
        unsigned short* fp = &bufA[tid * SF];
#pragma unroll
        for (int q = 0; q < 12; ++q) fp[256 + q] = f2bf(s[q]);
#pragma unroll
        for (int q = FEATD; q < K1PAD; ++q) fp[q] = 0;
        cd_s[tid][0] = dx; cd_s[tid][1] = dy; cd_s[tid][2] = dz;
    }
    // --- phase 2: gather h[row], h[col] -> bf16 feat ---
    {
        // need row/col indices; recompute per-thread from global (L1-hot)
        for (int idx = tid; idx < TE * 64; idx += 256) {
            const int e = idx >> 6, c4 = idx & 63;
            const int node = (c4 < 32) ? eidx[e0 + e] : eidx[EE + e0 + e];
            const int cc = (c4 < 32) ? c4 * 4 : (c4 - 32) * 4;
            float4 v = *(const float4*)&h[((size_t)b * NN + node) * FFdim + cc];
            ushort4 u;
            u.x = f2bf(v.x); u.y = f2bf(v.y); u.z = f2bf(v.z); u.w = f2bf(v.w);
            *(ushort4*)&bufA[e * SF + c4 * 4] = u;
        }
    }
    __syncthreads();

    // --- GEMM1: feat[64 x 288] @ w1T -> hmid[64 x 256], silu ---
    floatx4 acc[4][4];
#pragma unroll
    for (int i = 0; i < 4; ++i)
#pragma unroll
        for (int j = 0; j < 4; ++j)
#pragma unroll
            for (int q = 0; q < 4; ++q) acc[i][j][q] = 0.f;
#pragma unroll
    for (int ks = 0; ks < K1PAD / 32; ++ks) {
        const int kb = ks * 32 + koff;
        bf16x8 a[4], bfr[4];
#pragma unroll
        for (int rt = 0; rt < 4; ++rt)
            a[rt] = *(const bf16x8*)&bufA[(rt * 16 + lm) * SF + kb];
#pragma unroll
        for (int ct = 0; ct < 4; ++ct)
            bfr[ct] = *(const bf16x8*)&w1T[(size_t)(w * 64 + ct * 16 + lm) * K1PAD + kb];
#pragma unroll
        for (int rt = 0; rt < 4; ++rt)
#pragma unroll
            for (int ct = 0; ct < 4; ++ct)
                acc[rt][ct] = __builtin_amdgcn_mfma_f32_16x16x32_bf16(
                    a[rt], bfr[ct], acc[rt][ct], 0, 0, 0);
    }
#pragma unroll
    for (int ct = 0; ct < 4; ++ct) {
        const int col = w * 64 + ct * 16 + lm;
        const float bias = b1[col];
#pragma unroll
        for (int rt = 0; rt < 4; ++rt)
#pragma unroll
            for (int reg = 0; reg < 4; ++reg) {
                const int row = rt * 16 + quad * 4 + reg;
                bufH[row * SH + col] = f2bf(silu_f(acc[rt][ct][reg] + bias));
            }
    }
    // no barrier: wave w's GEMM2 reads only the columns wave w wrote.

    // --- GEMM2: hmid[:, w*64 : w*64+64] @ w2T(head w) -> combined cols of head w ---
    floatx4 acc2[4][4];
#pragma unroll
    for (int i = 0; i < 4; ++i)
#pragma unroll
        for (int j = 0; j < 4; ++j)
#pragma unroll
            for (int q = 0; q < 4; ++q) acc2[i][j][q] = 0.f;
#pragma unroll
    for (int ks = 0; ks < 2; ++ks) {
        const int kb = ks * 32 + koff;
        bf16x8 a[4], bfr[4];
#pragma unroll
        for (int rt = 0; rt < 4; ++rt)
            a[rt] = *(const bf16x8*)&bufH[(rt * 16 + lm) * SH + w * 64 + kb];
#pragma unroll
        for (int ct = 0; ct < 4; ++ct)
            bfr[ct] = *(const bf16x8*)&w2T[(size_t)(w * 64 + ct * 16 + lm) * 64 + kb];
#pragma unroll
        for (int rt = 0; rt < 4; ++rt)
#pragma unroll
            for (int ct = 0; ct < 4; ++ct)
                acc2[rt][ct] = __builtin_amdgcn_mfma_f32_16x16x32_bf16(
                    a[rt], bfr[ct], acc2[rt][ct], 0, 0, 0);
    }
    // --- bias + LayerNorm partials ---
    float bias2[4];
#pragma unroll
    for (int ct = 0; ct < 4; ++ct) bias2[ct] = b2[w * 64 + ct * 16 + lm];
#pragma unroll
    for (int rt = 0; rt < 4; ++rt)
#pragma unroll
        for (int reg = 0; reg < 4; ++reg) {
            float s = 0.f, s2 = 0.f;
#pragma unroll
            for (int ct = 0; ct < 4; ++ct) {
                float v = acc2[rt][ct][reg] + bias2[ct];
                acc2[rt][ct][reg] = v;
                s += v; s2 += v * v;
            }
#pragma unroll
            for (int m = 1; m <= 8; m <<= 1) {
                s += __shfl_xor(s, m, 64);
                s2 += __shfl_xor(s2, m, 64);
            }
            if (lm == 0) {
                const int row = rt * 16 + quad * 4 + reg;
                lnred[row][w] = make_float2(s, s2);
            }
        }
    __syncthreads();     // also: all waves past GEMM1 A-reads -> bufA reusable
    if (tid < TE) {
        float s = 0.f, s2 = 0.f;
#pragma unroll
        for (int ww = 0; ww < 4; ++ww) { s += lnred[tid][ww].x; s2 += lnred[tid][ww].y; }
        float mean = s * (1.0f / 256.0f);
        float var = s2 * (1.0f / 256.0f) - mean * mean;
        mu_s[tid] = mean;
        rs_s[tid] = rsqrtf(var + 1e-5f);
    }
    __syncthreads();
    {
        float gv[4], bv[4];
#pragma unroll
        for (int ct = 0; ct < 4; ++ct) {
            const int col = w * 64 + ct * 16 + lm;
            gv[ct] = lng[col]; bv[ct] = lnb[col];
        }
#pragma unroll
        for (int rt = 0; rt < 4; ++rt)
#pragma unroll
            for (int reg = 0; reg < 4; ++reg) {
                const int row = rt * 16 + quad * 4 + reg;
                const float mu = mu_s[row], rs = rs_s[row];
#pragma unroll
                for (int ct = 0; ct < 4; ++ct) {
                    const int col = w * 64 + ct * 16 + lm;
                    float v = (acc2[rt][ct][reg] - mu) * rs * gv[ct] + bv[ct];
                    bufA[row * SH + col] = f2bf(v);   // ef overlays bufA
                }
            }
    }
    __syncthreads();

    // --- GEMM3: ef[64 x 256] @ cw1T -> silu -> dot cw2 -> w per edge ---
    floatx4 acc3[4][4];
#pragma unroll
    for (int i = 0; i < 4; ++i)
#pragma unroll
        for (int j = 0; j < 4; ++j)
#pragma unroll
            for (int q = 0; q < 4; ++q) acc3[i][j][q] = 0.f;
#pragma unroll
    for (int ks = 0; ks < 8; ++ks) {
        const int kb = ks * 32 + koff;
        bf16x8 a[4], bfr[4];
#pragma unroll
        for (int rt = 0; rt < 4; ++rt)
            a[rt] = *(const bf16x8*)&bufA[(rt * 16 + lm) * SH + kb];
#pragma unroll
        for (int ct = 0; ct < 4; ++ct)
            bfr[ct] = *(const bf16x8*)&cw1T[(size_t)(w * 64 + ct * 16 + lm) * 256 + kb];
#pragma unroll
        for (int rt = 0; rt < 4; ++rt)
#pragma unroll
            for (int ct = 0; ct < 4; ++ct)
                acc3[rt][ct] = __builtin_amdgcn_mfma_f32_16x16x32_bf16(
                    a[rt], bfr[ct], acc3[rt][ct], 0, 0, 0);
    }
    {
        float cb[4], cwv[4];
#pragma unroll
        for (int ct = 0; ct < 4; ++ct) {
            const int col = w * 64 + ct * 16 + lm;
            cb[ct] = cb1[col]; cwv[ct] = cw2[col];
        }
#pragma unroll
        for (int rt = 0; rt < 4; ++rt)
#pragma unroll
            for (int reg = 0; reg < 4; ++reg) {
                float s = 0.f;
#pragma unroll
                for (int ct = 0; ct < 4; ++ct)
                    s += silu_f(acc3[rt][ct][reg] + cb[ct]) * cwv[ct];
#pragma unroll
                for (int m = 1; m <= 8; m <<= 1) s += __shfl_xor(s, m, 64);
                if (lm == 0) wpart[rt * 16 + quad * 4 + reg][w] = s;
            }
    }
    __syncthreads();
    if (tid < TE)
        w_s[tid] = wpart[tid][0] + wpart[tid][1] + wpart[tid][2] + wpart[tid][3];
    __syncthreads();

    // --- scatter: agg += edge_feat (bf16->f32) ; coord_out += coord_diff * w ---
    for (int i = tid; i < TE * 128; i += 256) {
        const int e = i >> 7, c2 = (i & 127) * 2;
        unsigned int u = *(const unsigned int*)&bufA[e * SH + c2];
        float v0 = __uint_as_float(u << 16);
        float v1 = __uint_as_float(u & 0xffff0000u);
        const size_t base = ((size_t)b * NN + row_s[e]) * HHdim + c2;
        atomicAdd(&agg[base], v0);
        atomicAdd(&agg[base + 1], v1);
    }
    if (tid < TE * 3) {
        const int e = tid / 3, ax = tid % 3;
        atomicAdd(&coord_out[((size_t)b * NN + row_s[e]) * 3 + ax],
                  cd_s[e][ax] * w_s[e]);
    }
}

// ---------------------------------------------------------------------------
// node kernel (fp32): one block = 64 node-rows. 256 threads.
__global__ __launch_bounds__(256, 1)
void node_kernel(const float* __restrict__ h,
                 const float* __restrict__ agg,
                 const float* __restrict__ nw1, const float* __restrict__ nb1,
                 const float* __restrict__ nw2, const float* __restrict__ nb2,
                 float* __restrict__ hout) {
    __shared__ float buf[TE * LDN];
    const int tid = threadIdx.x;
    const size_t m0 = (size_t)blockIdx.x * TE;
    const int jg = tid & 31, eg = tid >> 5;
    const int et = eg * 8;

    for (int idx = tid; idx < TE * 96; idx += 256) {
        const int r = idx / 96, c4 = idx % 96;
        const size_t m = m0 + r;
        float4 v = (c4 < 32)
            ? *(const float4*)&h[m * FFdim + c4 * 4]
            : *(const float4*)&agg[m * HHdim + (c4 - 32) * 4];
        *(float4*)&buf[r * LDN + c4 * 4] = v;
    }
    __syncthreads();

    const int j0 = jg * 8;
    float acc[8][8];
#pragma unroll
    for (int i = 0; i < 8; ++i)
#pragma unroll
        for (int j = 0; j < 8; ++j) acc[i][j] = 0.f;
    gemm8x8<(FFdim + HHdim) / 4>(&buf[et * LDN], LDN, &nw1[j0], HHdim, acc);
    float bias1[8];
#pragma unroll
    for (int jj = 0; jj < 8; ++jj) bias1[jj] = nb1[j0 + jj];
    __syncthreads();
#pragma unroll
    for (int e = 0; e < 8; ++e) {
        float4 o0, o1;
        o0.x = silu_f(acc[e][0] + bias1[0]); o0.y = silu_f(acc[e][1] + bias1[1]);
        o0.z = silu_f(acc[e][2] + bias1[2]); o0.w = silu_f(acc[e][3] + bias1[3]);
        o1.x = silu_f(acc[e][4] + bias1[4]); o1.y = silu_f(acc[e][5] + bias1[5]);
        o1.z = silu_f(acc[e][6] + bias1[6]); o1.w = silu_f(acc[e][7] + bias1[7]);
        *(float4*)&buf[(et + e) * LDN + j0] = o0;
        *(float4*)&buf[(et + e) * LDN + j0 + 4] = o1;
    }
    __syncthreads();

    const int j0b = jg * 4;
    float accb[8][4];
#pragma unroll
    for (int i = 0; i < 8; ++i)
#pragma unroll
        for (int j = 0; j < 4; ++j) accb[i][j] = 0.f;
    gemm8x4<HHdim / 4>(&buf[et * LDN], LDN, &nw2[j0b], FFdim, accb);
    float4 bb = *(const float4*)&nb2[j0b];
#pragma unroll
    for (int e = 0; e < 8; ++e) {
        const size_t m = m0 + et + e;
        float4 hv = *(const float4*)&h[m * FFdim + j0b];
        float4 o;
        o.x = accb[e][0] + bb.x + hv.x;
        o.y = accb[e][1] + bb.y + hv.y;
        o.z = accb[e][2] + bb.z + hv.z;
        o.w = accb[e][3] + bb.w + hv.w;
        *(float4*)&hout[m * FFdim + j0b] = o;
    }
}

// ---------------------------------------------------------------------------
extern "C" void kernel_launch(void* const* d_in, const int* in_sizes, int n_in,
                              void* d_out, int out_size, void* d_ws, size_t ws_size,
                              hipStream_t stream) {
    const float* h     = (const float*)d_in[0];
    const float* coord = (const float*)d_in[1];
    const int*   eidx  = (const int*)d_in[2];
    const float* w1    = (const float*)d_in[3];
    const float* b1    = (const float*)d_in[4];
    const float* w2    = (const float*)d_in[5];
    const float* b2    = (const float*)d_in[6];
    const float* lng   = (const float*)d_in[7];
    const float* lnb   = (const float*)d_in[8];
    const float* nw1   = (const float*)d_in[9];
    const float* nb1   = (const float*)d_in[10];
    const float* nw2   = (const float*)d_in[11];
    const float* nb2   = (const float*)d_in[12];
    const float* cw1   = (const float*)d_in[13];
    const float* cb1   = (const float*)d_in[14];
    const float* cw2   = (const float*)d_in[15];

    float* hout = (float*)d_out;
    float* coord_out = hout + (size_t)BB * NN * FFdim;

    char* wsB = (char*)d_ws;
    float* agg = (float*)wsB;                                  // 16 MiB
    unsigned short* w1T  = (unsigned short*)(wsB + (size_t)BB * NN * HHdim * 4);
    unsigned short* w2T  = w1T + W1T_ELEMS;
    unsigned short* cw1T = w2T + W2T_ELEMS;

    hipLaunchKernelGGL(prep_weights,
                       dim3((W1T_ELEMS + W2T_ELEMS + CW1T_ELEMS) / 256), dim3(256),
                       0, stream, w1, w2, cw1, w1T, w2T, cw1T);
    hipLaunchKernelGGL(init_kernel, dim3((BB * NN * HHdim / 4) / 256), dim3(256),
                       0, stream, (float4*)agg, coord_out, coord);
    hipLaunchKernelGGL(edge_kernel, dim3(EE / TE, BB), dim3(256), 0, stream,
                       h, coord, eidx, w1T, b1, w2T, b2, lng, lnb, cw1T, cb1, cw2,
                       agg, coord_out);
    hipLaunchKernelGGL(node_kernel, dim3((BB * NN) / TE), dim3(256), 0, stream,
                       h, agg, nw1, nb1, nw2, nb2, hout);
}

// Round 3
// 508.374 us; speedup vs baseline: 2.2438x; 1.3831x over previous
//
#include <hip/hip_runtime.h>
#include <cstdint>
#include <cstddef>

#define BB 2
#define NN 8192
#define EE 131072
#define FFdim 128
#define HHdim 256
#define NHEAD 4
#define DHEAD 64
#define FEATD 268
#define K1PAD 288        // FEAT padded to multiple of 32
#define SF 296           // featA LDS row stride (ushort); 592B: 2-way bank alias, free
#define SH 264           // hmid/ef LDS row stride (ushort); 528B (16B-aligned), 2-way, free
#define LDN 388          // node LDS row stride (floats)
#define TE 64

typedef short bf16x8 __attribute__((ext_vector_type(8)));
typedef float floatx4 __attribute__((ext_vector_type(4)));

__device__ __forceinline__ float silu_f(float x) {
    return x / (1.0f + __expf(-x));
}
__device__ __forceinline__ unsigned short f2bf(float x) {
    unsigned int u = __float_as_uint(x);
    unsigned int r = (u + 0x7fffu + ((u >> 16) & 1u)) >> 16;
    return (unsigned short)r;
}
__device__ __forceinline__ float bf2f(unsigned short u) {
    return __uint_as_float(((unsigned int)u) << 16);
}

// ---------------------------------------------------------------------------
// fp32 8x8 register-tile GEMM helpers (node kernel)
template <int NK4>
__device__ __forceinline__ void gemm8x8(const float* __restrict__ lA, int ldA,
                                        const float* __restrict__ wB, int ldB,
                                        float (&acc)[8][8]) {
#pragma unroll 2
    for (int k4 = 0; k4 < NK4; ++k4) {
        const int kk = k4 * 4;
        float a4[8][4];
#pragma unroll
        for (int e = 0; e < 8; ++e) {
            float4 v = *(const float4*)(lA + e * ldA + kk);
            a4[e][0] = v.x; a4[e][1] = v.y; a4[e][2] = v.z; a4[e][3] = v.w;
        }
#pragma unroll
        for (int f = 0; f < 4; ++f) {
            const float* wr = wB + (size_t)(kk + f) * ldB;
            float4 w0 = *(const float4*)(wr);
            float4 w1v = *(const float4*)(wr + 4);
#pragma unroll
            for (int e = 0; e < 8; ++e) {
                float av = a4[e][f];
                acc[e][0] += av * w0.x;  acc[e][1] += av * w0.y;
                acc[e][2] += av * w0.z;  acc[e][3] += av * w0.w;
                acc[e][4] += av * w1v.x; acc[e][5] += av * w1v.y;
                acc[e][6] += av * w1v.z; acc[e][7] += av * w1v.w;
            }
        }
    }
}

template <int NK4>
__device__ __forceinline__ void gemm8x4(const float* __restrict__ lA, int ldA,
                                        const float* __restrict__ wB, int ldB,
                                        float (&acc)[8][4]) {
#pragma unroll 2
    for (int k4 = 0; k4 < NK4; ++k4) {
        const int kk = k4 * 4;
        float a4[8][4];
#pragma unroll
        for (int e = 0; e < 8; ++e) {
            float4 v = *(const float4*)(lA + e * ldA + kk);
            a4[e][0] = v.x; a4[e][1] = v.y; a4[e][2] = v.z; a4[e][3] = v.w;
        }
#pragma unroll
        for (int f = 0; f < 4; ++f) {
            const float* wr = wB + (size_t)(kk + f) * ldB;
            float4 w0 = *(const float4*)(wr);
#pragma unroll
            for (int e = 0; e < 8; ++e) {
                float av = a4[e][f];
                acc[e][0] += av * w0.x; acc[e][1] += av * w0.y;
                acc[e][2] += av * w0.z; acc[e][3] += av * w0.w;
            }
        }
    }
}

// ---------------------------------------------------------------------------
// prep: fp32 weights -> transposed bf16 layouts; also zero CSR counts.
#define W1T_ELEMS (256 * K1PAD)
#define W2T_ELEMS (256 * 64)
#define CW1T_ELEMS (256 * 256)
#define WT_TOT (W1T_ELEMS + W2T_ELEMS + CW1T_ELEMS)
__global__ void prep_weights(const float* __restrict__ w1,
                             const float* __restrict__ w2,
                             const float* __restrict__ cw1,
                             unsigned short* __restrict__ w1T,
                             unsigned short* __restrict__ w2T,
                             unsigned short* __restrict__ cw1T,
                             int* __restrict__ counts) {
    int idx = blockIdx.x * blockDim.x + threadIdx.x;
    if (idx < W1T_ELEMS) {
        int n = idx / K1PAD, k = idx % K1PAD;
        int hh = n >> 6, d = n & 63;
        float v = (k < FEATD) ? w1[((size_t)hh * FEATD + k) * DHEAD + d] : 0.f;
        w1T[idx] = f2bf(v);
    } else if (idx < W1T_ELEMS + W2T_ELEMS) {
        int j = idx - W1T_ELEMS;
        int hh = j >> 12, dout = (j >> 6) & 63, din = j & 63;
        w2T[j] = f2bf(w2[(size_t)hh * 4096 + din * 64 + dout]);
    } else if (idx < WT_TOT) {
        int j = idx - (W1T_ELEMS + W2T_ELEMS);
        int n = j >> 8, k = j & 255;
        cw1T[j] = f2bf(cw1[k * 256 + n]);
    } else if (idx < WT_TOT + NN) {
        counts[idx - WT_TOT] = 0;
    }
}

// ---------------------------------------------------------------------------
// CSR build (rows shared across batches)
__global__ void csr_count(const int* __restrict__ eidx, int* __restrict__ counts) {
    int e = blockIdx.x * 256 + threadIdx.x;
    atomicAdd(&counts[eidx[e]], 1);
}

__global__ void csr_scan(const int* __restrict__ counts,
                         int* __restrict__ offsets,
                         int* __restrict__ cursor) {
    __shared__ int tmp[256];
    __shared__ int base_s;
    if (threadIdx.x == 0) base_s = 0;
    __syncthreads();
    for (int c = 0; c < NN; c += 256) {
        int v = counts[c + threadIdx.x];
        tmp[threadIdx.x] = v;
        __syncthreads();
        for (int off = 1; off < 256; off <<= 1) {
            int t = (threadIdx.x >= off) ? tmp[threadIdx.x - off] : 0;
            __syncthreads();
            tmp[threadIdx.x] += t;
            __syncthreads();
        }
        int excl = base_s + tmp[threadIdx.x] - v;
        offsets[c + threadIdx.x] = excl;
        cursor[c + threadIdx.x] = excl;
        __syncthreads();
        if (threadIdx.x == 255) base_s += tmp[255];
        __syncthreads();
    }
    if (threadIdx.x == 0) offsets[NN] = base_s;
}

__global__ void csr_fill(const int* __restrict__ eidx,
                         int* __restrict__ cursor, int* __restrict__ elist) {
    int e = blockIdx.x * 256 + threadIdx.x;
    int r = eidx[e];
    int pos = atomicAdd(&cursor[r], 1);
    elist[pos] = e;
}

// ---------------------------------------------------------------------------
// edge kernel (MFMA bf16): one block = 64 edges of one batch, 256 threads.
// Streams edge_feat (bf16) and coord_diff*w (float4) to workspace — no atomics.
__global__ __launch_bounds__(256, 2)
void edge_kernel(const float* __restrict__ h,
                 const float* __restrict__ coord,
                 const int* __restrict__ eidx,
                 const unsigned short* __restrict__ w1T, const float* __restrict__ b1,
                 const unsigned short* __restrict__ w2T, const float* __restrict__ b2,
                 const float* __restrict__ lng, const float* __restrict__ lnb,
                 const unsigned short* __restrict__ cw1T, const float* __restrict__ cb1,
                 const float* __restrict__ cw2,
                 unsigned short* __restrict__ efb, float4* __restrict__ wd) {
    __shared__ unsigned short bufA[TE * SF];   // feat bf16; later reused as ef bf16
    __shared__ unsigned short bufH[TE * SH];   // hmid bf16
    __shared__ float cd_s[TE][3];
    __shared__ float2 lnred[TE][4];
    __shared__ float mu_s[TE], rs_s[TE];
    __shared__ float wpart[TE][4];

    const int tid = threadIdx.x;
    const int b = blockIdx.y;
    const int e0 = blockIdx.x * TE;
    const int lane = tid & 63;
    const int w = tid >> 6;          // wave id = column quarter / head
    const int lm = lane & 15;
    const int quad = lane >> 4;
    const int koff = quad * 8;

    // --- phase 1: geometry (one thread per edge) ---
    if (tid < TE) {
        const int e = e0 + tid;
        const int r = eidx[e], c = eidx[EE + e];
        const float* pi = coord + ((size_t)b * NN + r) * 3;
        const float* pk = coord + ((size_t)b * NN + c) * 3;
        float ci0 = pi[0], ci1 = pi[1], ci2 = pi[2];
        float ck0 = pk[0], ck1 = pk[1], ck2 = pk[2];
        float dx = ci0 - ck0, dy = ci1 - ck1, dz = ci2 - ck2;
        float radial = dx * dx + dy * dy + dz * dz;
        float dist = sqrtf(radial);
        float dotv = ci0 * ck0 + ci1 * ck1 + ci2 * ck2;
        float inva = 1.0f / (dist + 1e-8f);
        float a0 = dx * inva, a1 = dy * inva, a2 = dz * inva;
        float cr0 = ci1 * ck2 - ci2 * ck1;
        float cr1 = ci2 * ck0 - ci0 * ck2;
        float cr2 = ci0 * ck1 - ci1 * ck0;
        float nb = sqrtf(cr0 * cr0 + cr1 * cr1 + cr2 * cr2);
        float invb = 1.0f / (nb + 1e-8f);
        float b0 = cr0 * invb, b1v = cr1 * invb, b2v = cr2 * invb;
        float c0 = a1 * b2v - a2 * b1v;
        float c1 = a2 * b0 - a0 * b2v;
        float c2 = a0 * b1v - a1 * b0;
        float na = sqrtf(a0 * a0 + a1 * a1 + a2 * a2);
        float nbn = sqrtf(b0 * b0 + b1v * b1v + b2v * b2v);
        float nc = sqrtf(c0 * c0 + c1 * c1 + c2 * c2);
        bool bad = (na < 1e-6f) || (nbn < 1e-6f) || (nc < 1e-6f);
        float s[12];
        s[0] = radial; s[1] = dist; s[2] = dotv;
        if (bad) {
            s[3] = 1.f; s[4] = 0.f; s[5] = 0.f;
            s[6] = 0.f; s[7] = 1.f; s[8] = 0.f;
            s[9] = 0.f; s[10] = 0.f; s[11] = 1.f;
        } else {
            s[3] = a0;  s[4] = b0;  s[5] = c0;
            s[6] = a1;  s[7] = b1v; s[8] = c1;
            s[9] = a2;  s[10] = b2v; s[11] = c2;
        }
        unsigned short* fp = &bufA[tid * SF];
#pragma unroll
        for (int q = 0; q < 12; ++q) fp[256 + q] = f2bf(s[q]);
#pragma unroll
        for (int q = FEATD; q < K1PAD; ++q) fp[q] = 0;
        cd_s[tid][0] = dx; cd_s[tid][1] = dy; cd_s[tid][2] = dz;
    }
    // --- phase 2: gather h[row], h[col] -> bf16 feat ---
    for (int idx = tid; idx < TE * 64; idx += 256) {
        const int e = idx >> 6, c4 = idx & 63;
        const int node = (c4 < 32) ? eidx[e0 + e] : eidx[EE + e0 + e];
        const int cc = (c4 < 32) ? c4 * 4 : (c4 - 32) * 4;
        float4 v = *(const float4*)&h[((size_t)b * NN + node) * FFdim + cc];
        ushort4 u;
        u.x = f2bf(v.x); u.y = f2bf(v.y); u.z = f2bf(v.z); u.w = f2bf(v.w);
        *(ushort4*)&bufA[e * SF + c4 * 4] = u;
    }
    __syncthreads();

    // --- GEMM1: feat[64 x 288] @ w1T -> hmid[64 x 256], silu ---
    floatx4 acc[4][4];
#pragma unroll
    for (int i = 0; i < 4; ++i)
#pragma unroll
        for (int j = 0; j < 4; ++j)
#pragma unroll
            for (int q = 0; q < 4; ++q) acc[i][j][q] = 0.f;
#pragma unroll
    for (int ks = 0; ks < K1PAD / 32; ++ks) {
        const int kb = ks * 32 + koff;
        bf16x8 a[4], bfr[4];
#pragma unroll
        for (int rt = 0; rt < 4; ++rt)
            a[rt] = *(const bf16x8*)&bufA[(rt * 16 + lm) * SF + kb];
#pragma unroll
        for (int ct = 0; ct < 4; ++ct)
            bfr[ct] = *(const bf16x8*)&w1T[(size_t)(w * 64 + ct * 16 + lm) * K1PAD + kb];
#pragma unroll
        for (int rt = 0; rt < 4; ++rt)
#pragma unroll
            for (int ct = 0; ct < 4; ++ct)
                acc[rt][ct] = __builtin_amdgcn_mfma_f32_16x16x32_bf16(
                    a[rt], bfr[ct], acc[rt][ct], 0, 0, 0);
    }
#pragma unroll
    for (int ct = 0; ct < 4; ++ct) {
        const int col = w * 64 + ct * 16 + lm;
        const float bias = b1[col];
#pragma unroll
        for (int rt = 0; rt < 4; ++rt)
#pragma unroll
            for (int reg = 0; reg < 4; ++reg) {
                const int row = rt * 16 + quad * 4 + reg;
                bufH[row * SH + col] = f2bf(silu_f(acc[rt][ct][reg] + bias));
            }
    }
    // no barrier: wave w's GEMM2 reads only columns wave w wrote.

    // --- GEMM2: hmid[:, w*64 .. +64] @ w2T(head w) ---
    floatx4 acc2[4][4];
#pragma unroll
    for (int i = 0; i < 4; ++i)
#pragma unroll
        for (int j = 0; j < 4; ++j)
#pragma unroll
            for (int q = 0; q < 4; ++q) acc2[i][j][q] = 0.f;
#pragma unroll
    for (int ks = 0; ks < 2; ++ks) {
        const int kb = ks * 32 + koff;
        bf16x8 a[4], bfr[4];
#pragma unroll
        for (int rt = 0; rt < 4; ++rt)
            a[rt] = *(const bf16x8*)&bufH[(rt * 16 + lm) * SH + w * 64 + kb];
#pragma unroll
        for (int ct = 0; ct < 4; ++ct)
            bfr[ct] = *(const bf16x8*)&w2T[(size_t)(w * 64 + ct * 16 + lm) * 64 + kb];
#pragma unroll
        for (int rt = 0; rt < 4; ++rt)
#pragma unroll
            for (int ct = 0; ct < 4; ++ct)
                acc2[rt][ct] = __builtin_amdgcn_mfma_f32_16x16x32_bf16(
                    a[rt], bfr[ct], acc2[rt][ct], 0, 0, 0);
    }
    // --- bias + LayerNorm ---
    float bias2[4];
#pragma unroll
    for (int ct = 0; ct < 4; ++ct) bias2[ct] = b2[w * 64 + ct * 16 + lm];
#pragma unroll
    for (int rt = 0; rt < 4; ++rt)
#pragma unroll
        for (int reg = 0; reg < 4; ++reg) {
            float s = 0.f, s2 = 0.f;
#pragma unroll
            for (int ct = 0; ct < 4; ++ct) {
                float v = acc2[rt][ct][reg] + bias2[ct];
                acc2[rt][ct][reg] = v;
                s += v; s2 += v * v;
            }
#pragma unroll
            for (int m = 1; m <= 8; m <<= 1) {
                s += __shfl_xor(s, m, 64);
                s2 += __shfl_xor(s2, m, 64);
            }
            if (lm == 0) {
                const int row = rt * 16 + quad * 4 + reg;
                lnred[row][w] = make_float2(s, s2);
            }
        }
    __syncthreads();
    if (tid < TE) {
        float s = 0.f, s2 = 0.f;
#pragma unroll
        for (int ww = 0; ww < 4; ++ww) { s += lnred[tid][ww].x; s2 += lnred[tid][ww].y; }
        float mean = s * (1.0f / 256.0f);
        float var = s2 * (1.0f / 256.0f) - mean * mean;
        mu_s[tid] = mean;
        rs_s[tid] = rsqrtf(var + 1e-5f);
    }
    __syncthreads();
    {
        float gv[4], bv[4];
#pragma unroll
        for (int ct = 0; ct < 4; ++ct) {
            const int col = w * 64 + ct * 16 + lm;
            gv[ct] = lng[col]; bv[ct] = lnb[col];
        }
#pragma unroll
        for (int rt = 0; rt < 4; ++rt)
#pragma unroll
            for (int reg = 0; reg < 4; ++reg) {
                const int row = rt * 16 + quad * 4 + reg;
                const float mu = mu_s[row], rs = rs_s[row];
#pragma unroll
                for (int ct = 0; ct < 4; ++ct) {
                    const int col = w * 64 + ct * 16 + lm;
                    float v = (acc2[rt][ct][reg] - mu) * rs * gv[ct] + bv[ct];
                    bufA[row * SH + col] = f2bf(v);   // ef overlays bufA
                }
            }
    }
    __syncthreads();

    // --- GEMM3: ef[64 x 256] @ cw1T -> silu -> dot cw2 -> w per edge ---
    floatx4 acc3[4][4];
#pragma unroll
    for (int i = 0; i < 4; ++i)
#pragma unroll
        for (int j = 0; j < 4; ++j)
#pragma unroll
            for (int q = 0; q < 4; ++q) acc3[i][j][q] = 0.f;
#pragma unroll
    for (int ks = 0; ks < 8; ++ks) {
        const int kb = ks * 32 + koff;
        bf16x8 a[4], bfr[4];
#pragma unroll
        for (int rt = 0; rt < 4; ++rt)
            a[rt] = *(const bf16x8*)&bufA[(rt * 16 + lm) * SH + kb];
#pragma unroll
        for (int ct = 0; ct < 4; ++ct)
            bfr[ct] = *(const bf16x8*)&cw1T[(size_t)(w * 64 + ct * 16 + lm) * 256 + kb];
#pragma unroll
        for (int rt = 0; rt < 4; ++rt)
#pragma unroll
            for (int ct = 0; ct < 4; ++ct)
                acc3[rt][ct] = __builtin_amdgcn_mfma_f32_16x16x32_bf16(
                    a[rt], bfr[ct], acc3[rt][ct], 0, 0, 0);
    }
    {
        float cb[4], cwv[4];
#pragma unroll
        for (int ct = 0; ct < 4; ++ct) {
            const int col = w * 64 + ct * 16 + lm;
            cb[ct] = cb1[col]; cwv[ct] = cw2[col];
        }
#pragma unroll
        for (int rt = 0; rt < 4; ++rt)
#pragma unroll
            for (int reg = 0; reg < 4; ++reg) {
                float s = 0.f;
#pragma unroll
                for (int ct = 0; ct < 4; ++ct)
                    s += silu_f(acc3[rt][ct][reg] + cb[ct]) * cwv[ct];
#pragma unroll
                for (int m = 1; m <= 8; m <<= 1) s += __shfl_xor(s, m, 64);
                if (lm == 0) wpart[rt * 16 + quad * 4 + reg][w] = s;
            }
    }
    __syncthreads();

    // --- streaming outputs: ef rows (bf16) + coord_diff * w (float4) ---
    if (tid < TE) {
        float ww = wpart[tid][0] + wpart[tid][1] + wpart[tid][2] + wpart[tid][3];
        float4 o = { cd_s[tid][0] * ww, cd_s[tid][1] * ww, cd_s[tid][2] * ww, 0.f };
        wd[(size_t)b * EE + e0 + tid] = o;
    }
    {
        unsigned short* dst = &efb[((size_t)b * EE + e0) * HHdim];
        for (int idx = tid; idx < TE * 32; idx += 256) {   // 32 x 16B per row
            const int e = idx >> 5, c = idx & 31;
            uint4 v = *(const uint4*)&bufA[e * SH + c * 8];
            *(uint4*)&dst[e * HHdim + c * 8] = v;
        }
    }
}

// ---------------------------------------------------------------------------
// gather kernel: one wave per node. Sums ef rows + wd vectors via CSR.
__global__ __launch_bounds__(256, 4)
void gather_kernel(const unsigned short* __restrict__ efb,
                   const float4* __restrict__ wd,
                   const int* __restrict__ offsets,
                   const int* __restrict__ elist,
                   const float* __restrict__ coord,
                   float* __restrict__ agg,
                   float* __restrict__ coord_out) {
    const int b = blockIdx.y;
    const int lane = threadIdx.x & 63;
    const int wv = threadIdx.x >> 6;
    const int n = blockIdx.x * 4 + wv;
    const int o0 = offsets[n], o1 = offsets[n + 1];
    float f0 = 0.f, f1 = 0.f, f2 = 0.f, f3 = 0.f;
    float sx = 0.f, sy = 0.f, sz = 0.f;
    for (int j = o0; j < o1; ++j) {
        const int e = elist[j];
        ushort4 u = *(const ushort4*)&efb[((size_t)b * EE + e) * HHdim + lane * 4];
        f0 += bf2f(u.x); f1 += bf2f(u.y); f2 += bf2f(u.z); f3 += bf2f(u.w);
        float4 wvv = wd[(size_t)b * EE + e];
        sx += wvv.x; sy += wvv.y; sz += wvv.z;
    }
    float4 o = { f0, f1, f2, f3 };
    *(float4*)&agg[((size_t)b * NN + n) * HHdim + lane * 4] = o;
    if (lane < 3) {
        const size_t cb = ((size_t)b * NN + n) * 3 + lane;
        float s = (lane == 0) ? sx : (lane == 1) ? sy : sz;
        coord_out[cb] = coord[cb] + s;
    }
}

// ---------------------------------------------------------------------------
// node kernel (fp32): one block = 64 node-rows. 256 threads.
__global__ __launch_bounds__(256, 1)
void node_kernel(const float* __restrict__ h,
                 const float* __restrict__ agg,
                 const float* __restrict__ nw1, const float* __restrict__ nb1,
                 const float* __restrict__ nw2, const float* __restrict__ nb2,
                 float* __restrict__ hout) {
    __shared__ float buf[TE * LDN];
    const int tid = threadIdx.x;
    const size_t m0 = (size_t)blockIdx.x * TE;
    const int jg = tid & 31, eg = tid >> 5;
    const int et = eg * 8;

    for (int idx = tid; idx < TE * 96; idx += 256) {
        const int r = idx / 96, c4 = idx % 96;
        const size_t m = m0 + r;
        float4 v = (c4 < 32)
            ? *(const float4*)&h[m * FFdim + c4 * 4]
            : *(const float4*)&agg[m * HHdim + (c4 - 32) * 4];
        *(float4*)&buf[r * LDN + c4 * 4] = v;
    }
    __syncthreads();

    const int j0 = jg * 8;
    float acc[8][8];
#pragma unroll
    for (int i = 0; i < 8; ++i)
#pragma unroll
        for (int j = 0; j < 8; ++j) acc[i][j] = 0.f;
    gemm8x8<(FFdim + HHdim) / 4>(&buf[et * LDN], LDN, &nw1[j0], HHdim, acc);
    float bias1[8];
#pragma unroll
    for (int jj = 0; jj < 8; ++jj) bias1[jj] = nb1[j0 + jj];
    __syncthreads();
#pragma unroll
    for (int e = 0; e < 8; ++e) {
        float4 o0, o1;
        o0.x = silu_f(acc[e][0] + bias1[0]); o0.y = silu_f(acc[e][1] + bias1[1]);
        o0.z = silu_f(acc[e][2] + bias1[2]); o0.w = silu_f(acc[e][3] + bias1[3]);
        o1.x = silu_f(acc[e][4] + bias1[4]); o1.y = silu_f(acc[e][5] + bias1[5]);
        o1.z = silu_f(acc[e][6] + bias1[6]); o1.w = silu_f(acc[e][7] + bias1[7]);
        *(float4*)&buf[(et + e) * LDN + j0] = o0;
        *(float4*)&buf[(et + e) * LDN + j0 + 4] = o1;
    }
    __syncthreads();

    const int j0b = jg * 4;
    float accb[8][4];
#pragma unroll
    for (int i = 0; i < 8; ++i)
#pragma unroll
        for (int j = 0; j < 4; ++j) accb[i][j] = 0.f;
    gemm8x4<HHdim / 4>(&buf[et * LDN], LDN, &nw2[j0b], FFdim, accb);
    float4 bb = *(const float4*)&nb2[j0b];
#pragma unroll
    for (int e = 0; e < 8; ++e) {
        const size_t m = m0 + et + e;
        float4 hv = *(const float4*)&h[m * FFdim + j0b];
        float4 o;
        o.x = accb[e][0] + bb.x + hv.x;
        o.y = accb[e][1] + bb.y + hv.y;
        o.z = accb[e][2] + bb.z + hv.z;
        o.w = accb[e][3] + bb.w + hv.w;
        *(float4*)&hout[m * FFdim + j0b] = o;
    }
}

// ---------------------------------------------------------------------------
extern "C" void kernel_launch(void* const* d_in, const int* in_sizes, int n_in,
                              void* d_out, int out_size, void* d_ws, size_t ws_size,
                              hipStream_t stream) {
    const float* h     = (const float*)d_in[0];
    const float* coord = (const float*)d_in[1];
    const int*   eidx  = (const int*)d_in[2];
    const float* w1    = (const float*)d_in[3];
    const float* b1    = (const float*)d_in[4];
    const float* w2    = (const float*)d_in[5];
    const float* b2    = (const float*)d_in[6];
    const float* lng   = (const float*)d_in[7];
    const float* lnb   = (const float*)d_in[8];
    const float* nw1   = (const float*)d_in[9];
    const float* nb1   = (const float*)d_in[10];
    const float* nw2   = (const float*)d_in[11];
    const float* nb2   = (const float*)d_in[12];
    const float* cw1   = (const float*)d_in[13];
    const float* cb1   = (const float*)d_in[14];
    const float* cw2   = (const float*)d_in[15];

    float* hout = (float*)d_out;
    float* coord_out = hout + (size_t)BB * NN * FFdim;

    char* p = (char*)d_ws;
    float* agg = (float*)p;                    p += (size_t)BB * NN * HHdim * 4;   // 16 MB
    float4* wd = (float4*)p;                   p += (size_t)BB * EE * 16;          // 4 MB
    unsigned short* efb = (unsigned short*)p;  p += (size_t)BB * EE * HHdim * 2;   // 134 MB
    unsigned short* w1T = (unsigned short*)p;  p += (size_t)W1T_ELEMS * 2;
    unsigned short* w2T = (unsigned short*)p;  p += (size_t)W2T_ELEMS * 2;
    unsigned short* cw1T = (unsigned short*)p; p += (size_t)CW1T_ELEMS * 2;
    int* counts = (int*)p;                     p += (size_t)NN * 4;
    int* offsets = (int*)p;                    p += (size_t)(NN + 1) * 4;
    int* cursor = (int*)p;                     p += (size_t)NN * 4;
    int* elist = (int*)p;                      p += (size_t)EE * 4;

    hipLaunchKernelGGL(prep_weights, dim3((WT_TOT + NN) / 256), dim3(256),
                       0, stream, w1, w2, cw1, w1T, w2T, cw1T, counts);
    hipLaunchKernelGGL(csr_count, dim3(EE / 256), dim3(256), 0, stream, eidx, counts);
    hipLaunchKernelGGL(csr_scan, dim3(1), dim3(256), 0, stream, counts, offsets, cursor);
    hipLaunchKernelGGL(csr_fill, dim3(EE / 256), dim3(256), 0, stream, eidx, cursor, elist);
    hipLaunchKernelGGL(edge_kernel, dim3(EE / TE, BB), dim3(256), 0, stream,
                       h, coord, eidx, w1T, b1, w2T, b2, lng, lnb, cw1T, cb1, cw2,
                       efb, wd);
    hipLaunchKernelGGL(gather_kernel, dim3(NN / 4, BB), dim3(256), 0, stream,
                       efb, wd, offsets, elist, coord, agg, coord_out);
    hipLaunchKernelGGL(node_kernel, dim3((BB * NN) / TE), dim3(256), 0, stream,
                       h, agg, nw1, nb1, nw2, nb2, hout);
}

// Round 4
// 366.047 us; speedup vs baseline: 3.1162x; 1.3888x over previous
//
#include <hip/hip_runtime.h>
#include <cstdint>
#include <cstddef>

#define BB 2
#define NN 8192
#define EE 131072
#define FFdim 128
#define HHdim 256
#define NHEAD 4
#define DHEAD 64
#define FEATD 268
#define K1PAD 288        // FEAT padded to multiple of 32
#define SF 296           // feat LDS row stride (ushort); 592B: 2-way bank alias, free
#define SH 264           // hmid/ef overlay stride (ushort); 528B, 16B-aligned, 2-way free
#define TE 64            // edges per edge-block
#define NT 32            // nodes per node-block
#define SA 392           // node A ([h|agg], 384) stride (ushort); 784B, 2-way free
#define SM 264           // node mid overlay stride (ushort)

typedef short bf16x8 __attribute__((ext_vector_type(8)));
typedef float floatx4 __attribute__((ext_vector_type(4)));

__device__ __forceinline__ float silu_f(float x) {
    return x / (1.0f + __expf(-x));
}
__device__ __forceinline__ unsigned short f2bf(float x) {
    unsigned int u = __float_as_uint(x);
    unsigned int r = (u + 0x7fffu + ((u >> 16) & 1u)) >> 16;
    return (unsigned short)r;
}
__device__ __forceinline__ float bf2f(unsigned short u) {
    return __uint_as_float(((unsigned int)u) << 16);
}

// ---------------------------------------------------------------------------
// prep: fp32 weights -> transposed bf16 layouts; zero CSR counts.
#define W1T_ELEMS (256 * K1PAD)
#define W2T_ELEMS (256 * 64)
#define CW1T_ELEMS (256 * 256)
#define NW1T_ELEMS (256 * 384)
#define NW2T_ELEMS (128 * 256)
#define WT_A (W1T_ELEMS)
#define WT_B (W1T_ELEMS + W2T_ELEMS)
#define WT_C (W1T_ELEMS + W2T_ELEMS + CW1T_ELEMS)
#define WT_D (WT_C + NW1T_ELEMS)
#define WT_E (WT_D + NW2T_ELEMS)
__global__ void prep_weights(const float* __restrict__ w1,
                             const float* __restrict__ w2,
                             const float* __restrict__ cw1,
                             const float* __restrict__ nw1,
                             const float* __restrict__ nw2,
                             unsigned short* __restrict__ w1T,
                             unsigned short* __restrict__ w2T,
                             unsigned short* __restrict__ cw1T,
                             unsigned short* __restrict__ nw1T,
                             unsigned short* __restrict__ nw2T,
                             int* __restrict__ counts) {
    int idx = blockIdx.x * blockDim.x + threadIdx.x;
    if (idx < WT_A) {
        int n = idx / K1PAD, k = idx % K1PAD;
        int hh = n >> 6, d = n & 63;
        float v = (k < FEATD) ? w1[((size_t)hh * FEATD + k) * DHEAD + d] : 0.f;
        w1T[idx] = f2bf(v);
    } else if (idx < WT_B) {
        int j = idx - WT_A;
        int hh = j >> 12, dout = (j >> 6) & 63, din = j & 63;
        w2T[j] = f2bf(w2[(size_t)hh * 4096 + din * 64 + dout]);
    } else if (idx < WT_C) {
        int j = idx - WT_B;
        int n = j >> 8, k = j & 255;
        cw1T[j] = f2bf(cw1[k * 256 + n]);
    } else if (idx < WT_D) {
        int j = idx - WT_C;
        int n = j / 384, k = j % 384;
        nw1T[j] = f2bf(nw1[k * 256 + n]);
    } else if (idx < WT_E) {
        int j = idx - WT_D;
        int n = j >> 8, k = j & 255;
        nw2T[j] = f2bf(nw2[k * 128 + n]);
    } else if (idx < WT_E + NN) {
        counts[idx - WT_E] = 0;
    }
}

// ---------------------------------------------------------------------------
// CSR build (row indices shared across batches)
__global__ void csr_count(const int* __restrict__ eidx, int* __restrict__ counts) {
    int e = blockIdx.x * 256 + threadIdx.x;
    atomicAdd(&counts[eidx[e]], 1);
}

// single block, 256 threads, each scans 32 contiguous counts; shfl wave-scan.
__global__ void csr_scan(const int* __restrict__ counts,
                         int* __restrict__ offsets,
                         int* __restrict__ cursor) {
    __shared__ int wsum[4];
    const int t = threadIdx.x;
    const int base = t * 32;
    int local[32];
    int s = 0;
#pragma unroll
    for (int i = 0; i < 32; ++i) { local[i] = counts[base + i]; s += local[i]; }
    const int lane = t & 63, w = t >> 6;
    int v = s;
#pragma unroll
    for (int off = 1; off < 64; off <<= 1) {
        int u = __shfl_up(v, off, 64);
        if (lane >= off) v += u;
    }
    if (lane == 63) wsum[w] = v;
    __syncthreads();
    int wbase = 0;
    for (int i = 0; i < w; ++i) wbase += wsum[i];
    int run = wbase + v - s;
#pragma unroll
    for (int i = 0; i < 32; ++i) {
        offsets[base + i] = run;
        cursor[base + i] = run;
        run += local[i];
    }
    if (t == 255) offsets[NN] = run;
}

__global__ void csr_fill(const int* __restrict__ eidx,
                         int* __restrict__ cursor, int* __restrict__ perm) {
    int e = blockIdx.x * 256 + threadIdx.x;
    int r = eidx[e];
    int pos = atomicAdd(&cursor[r], 1);
    perm[e] = pos;
}

// ---------------------------------------------------------------------------
// edge kernel (MFMA bf16): one block = 64 edges of one batch, 256 threads.
// Writes ef rows / wd vectors to CSR slot positions (perm) — streaming scatter.
__global__ __launch_bounds__(256, 3)
void edge_kernel(const float* __restrict__ h,
                 const float* __restrict__ coord,
                 const int* __restrict__ eidx,
                 const int* __restrict__ perm,
                 const unsigned short* __restrict__ w1T, const float* __restrict__ b1,
                 const unsigned short* __restrict__ w2T, const float* __restrict__ b2,
                 const float* __restrict__ lng, const float* __restrict__ lnb,
                 const unsigned short* __restrict__ cw1T, const float* __restrict__ cb1,
                 const float* __restrict__ cw2,
                 unsigned short* __restrict__ efb, float4* __restrict__ wd) {
    __shared__ unsigned short bufA[TE * SF];   // feat; then hmid/ef overlay (stride SH)
    __shared__ int slot_s[TE];
    __shared__ float cd_s[TE][3];
    __shared__ float2 lnred[TE][4];
    __shared__ float mu_s[TE], rs_s[TE];
    __shared__ float wpart[TE][4];

    const int tid = threadIdx.x;
    const int b = blockIdx.y;
    const int e0 = blockIdx.x * TE;
    const int lane = tid & 63;
    const int w = tid >> 6;          // wave id = column quarter / head
    const int lm = lane & 15;
    const int quad = lane >> 4;
    const int koff = quad * 8;

    // --- phase 1: geometry + slot (one thread per edge) ---
    if (tid < TE) {
        const int e = e0 + tid;
        const int r = eidx[e], c = eidx[EE + e];
        slot_s[tid] = perm[e];
        const float* pi = coord + ((size_t)b * NN + r) * 3;
        const float* pk = coord + ((size_t)b * NN + c) * 3;
        float ci0 = pi[0], ci1 = pi[1], ci2 = pi[2];
        float ck0 = pk[0], ck1 = pk[1], ck2 = pk[2];
        float dx = ci0 - ck0, dy = ci1 - ck1, dz = ci2 - ck2;
        float radial = dx * dx + dy * dy + dz * dz;
        float dist = sqrtf(radial);
        float dotv = ci0 * ck0 + ci1 * ck1 + ci2 * ck2;
        float inva = 1.0f / (dist + 1e-8f);
        float a0 = dx * inva, a1 = dy * inva, a2 = dz * inva;
        float cr0 = ci1 * ck2 - ci2 * ck1;
        float cr1 = ci2 * ck0 - ci0 * ck2;
        float cr2 = ci0 * ck1 - ci1 * ck0;
        float nb = sqrtf(cr0 * cr0 + cr1 * cr1 + cr2 * cr2);
        float invb = 1.0f / (nb + 1e-8f);
        float b0 = cr0 * invb, b1v = cr1 * invb, b2v = cr2 * invb;
        float c0 = a1 * b2v - a2 * b1v;
        float c1 = a2 * b0 - a0 * b2v;
        float c2 = a0 * b1v - a1 * b0;
        float na = sqrtf(a0 * a0 + a1 * a1 + a2 * a2);
        float nbn = sqrtf(b0 * b0 + b1v * b1v + b2v * b2v);
        float nc = sqrtf(c0 * c0 + c1 * c1 + c2 * c2);
        bool bad = (na < 1e-6f) || (nbn < 1e-6f) || (nc < 1e-6f);
        float s[12];
        s[0] = radial; s[1] = dist; s[2] = dotv;
        if (bad) {
            s[3] = 1.f; s[4] = 0.f; s[5] = 0.f;
            s[6] = 0.f; s[7] = 1.f; s[8] = 0.f;
            s[9] = 0.f; s[10] = 0.f; s[11] = 1.f;
        } else {
            s[3] = a0;  s[4] = b0;  s[5] = c0;
            s[6] = a1;  s[7] = b1v; s[8] = c1;
            s[9] = a2;  s[10] = b2v; s[11] = c2;
        }
        unsigned short* fp = &bufA[tid * SF];
#pragma unroll
        for (int q = 0; q < 12; ++q) fp[256 + q] = f2bf(s[q]);
#pragma unroll
        for (int q = FEATD; q < K1PAD; ++q) fp[q] = 0;
        cd_s[tid][0] = dx; cd_s[tid][1] = dy; cd_s[tid][2] = dz;
    }
    // --- phase 2: gather h[row], h[col] -> bf16 feat ---
    for (int idx = tid; idx < TE * 64; idx += 256) {
        const int e = idx >> 6, c4 = idx & 63;
        const int node = (c4 < 32) ? eidx[e0 + e] : eidx[EE + e0 + e];
        const int cc = (c4 < 32) ? c4 * 4 : (c4 - 32) * 4;
        float4 v = *(const float4*)&h[((size_t)b * NN + node) * FFdim + cc];
        ushort4 u;
        u.x = f2bf(v.x); u.y = f2bf(v.y); u.z = f2bf(v.z); u.w = f2bf(v.w);
        *(ushort4*)&bufA[e * SF + c4 * 4] = u;
    }
    __syncthreads();

    // --- GEMM1: feat[64 x 288] @ w1T -> hmid[64 x 256], silu ---
    floatx4 acc[4][4];
#pragma unroll
    for (int i = 0; i < 4; ++i)
#pragma unroll
        for (int j = 0; j < 4; ++j)
#pragma unroll
            for (int q = 0; q < 4; ++q) acc[i][j][q] = 0.f;
#pragma unroll
    for (int ks = 0; ks < K1PAD / 32; ++ks) {
        const int kb = ks * 32 + koff;
        bf16x8 a[4], bfr[4];
#pragma unroll
        for (int rt = 0; rt < 4; ++rt)
            a[rt] = *(const bf16x8*)&bufA[(rt * 16 + lm) * SF + kb];
#pragma unroll
        for (int ct = 0; ct < 4; ++ct)
            bfr[ct] = *(const bf16x8*)&w1T[(size_t)(w * 64 + ct * 16 + lm) * K1PAD + kb];
#pragma unroll
        for (int rt = 0; rt < 4; ++rt)
#pragma unroll
            for (int ct = 0; ct < 4; ++ct)
                acc[rt][ct] = __builtin_amdgcn_mfma_f32_16x16x32_bf16(
                    a[rt], bfr[ct], acc[rt][ct], 0, 0, 0);
    }
    __syncthreads();   // feat dead; bufA becomes hmid/ef (stride SH)
#pragma unroll
    for (int ct = 0; ct < 4; ++ct) {
        const int col = w * 64 + ct * 16 + lm;
        const float bias = b1[col];
#pragma unroll
        for (int rt = 0; rt < 4; ++rt)
#pragma unroll
            for (int reg = 0; reg < 4; ++reg) {
                const int row = rt * 16 + quad * 4 + reg;
                bufA[row * SH + col] = f2bf(silu_f(acc[rt][ct][reg] + bias));
            }
    }
    // wave-local: wave w's GEMM2 reads only the columns wave w wrote.

    // --- GEMM2: hmid[:, w*64 .. +64] @ w2T(head w) ---
    floatx4 acc2[4][4];
#pragma unroll
    for (int i = 0; i < 4; ++i)
#pragma unroll
        for (int j = 0; j < 4; ++j)
#pragma unroll
            for (int q = 0; q < 4; ++q) acc2[i][j][q] = 0.f;
#pragma unroll
    for (int ks = 0; ks < 2; ++ks) {
        const int kb = ks * 32 + koff;
        bf16x8 a[4], bfr[4];
#pragma unroll
        for (int rt = 0; rt < 4; ++rt)
            a[rt] = *(const bf16x8*)&bufA[(rt * 16 + lm) * SH + w * 64 + kb];
#pragma unroll
        for (int ct = 0; ct < 4; ++ct)
            bfr[ct] = *(const bf16x8*)&w2T[(size_t)(w * 64 + ct * 16 + lm) * 64 + kb];
#pragma unroll
        for (int rt = 0; rt < 4; ++rt)
#pragma unroll
            for (int ct = 0; ct < 4; ++ct)
                acc2[rt][ct] = __builtin_amdgcn_mfma_f32_16x16x32_bf16(
                    a[rt], bfr[ct], acc2[rt][ct], 0, 0, 0);
    }
    // --- bias + LayerNorm ---
    float bias2[4];
#pragma unroll
    for (int ct = 0; ct < 4; ++ct) bias2[ct] = b2[w * 64 + ct * 16 + lm];
#pragma unroll
    for (int rt = 0; rt < 4; ++rt)
#pragma unroll
        for (int reg = 0; reg < 4; ++reg) {
            float s = 0.f, s2 = 0.f;
#pragma unroll
            for (int ct = 0; ct < 4; ++ct) {
                float v = acc2[rt][ct][reg] + bias2[ct];
                acc2[rt][ct][reg] = v;
                s += v; s2 += v * v;
            }
#pragma unroll
            for (int m = 1; m <= 8; m <<= 1) {
                s += __shfl_xor(s, m, 64);
                s2 += __shfl_xor(s2, m, 64);
            }
            if (lm == 0) {
                const int row = rt * 16 + quad * 4 + reg;
                lnred[row][w] = make_float2(s, s2);
            }
        }
    __syncthreads();
    if (tid < TE) {
        float s = 0.f, s2 = 0.f;
#pragma unroll
        for (int ww = 0; ww < 4; ++ww) { s += lnred[tid][ww].x; s2 += lnred[tid][ww].y; }
        float mean = s * (1.0f / 256.0f);
        float var = s2 * (1.0f / 256.0f) - mean * mean;
        mu_s[tid] = mean;
        rs_s[tid] = rsqrtf(var + 1e-5f);
    }
    __syncthreads();
    {
        float gv[4], bv[4];
#pragma unroll
        for (int ct = 0; ct < 4; ++ct) {
            const int col = w * 64 + ct * 16 + lm;
            gv[ct] = lng[col]; bv[ct] = lnb[col];
        }
#pragma unroll
        for (int rt = 0; rt < 4; ++rt)
#pragma unroll
            for (int reg = 0; reg < 4; ++reg) {
                const int row = rt * 16 + quad * 4 + reg;
                const float mu = mu_s[row], rs = rs_s[row];
#pragma unroll
                for (int ct = 0; ct < 4; ++ct) {
                    const int col = w * 64 + ct * 16 + lm;
                    float v = (acc2[rt][ct][reg] - mu) * rs * gv[ct] + bv[ct];
                    bufA[row * SH + col] = f2bf(v);   // ef overwrites own hmid cols
                }
            }
    }
    __syncthreads();

    // --- GEMM3: ef[64 x 256] @ cw1T -> silu -> dot cw2 -> w per edge ---
    floatx4 acc3[4][4];
#pragma unroll
    for (int i = 0; i < 4; ++i)
#pragma unroll
        for (int j = 0; j < 4; ++j)
#pragma unroll
            for (int q = 0; q < 4; ++q) acc3[i][j][q] = 0.f;
#pragma unroll
    for (int ks = 0; ks < 8; ++ks) {
        const int kb = ks * 32 + koff;
        bf16x8 a[4], bfr[4];
#pragma unroll
        for (int rt = 0; rt < 4; ++rt)
            a[rt] = *(const bf16x8*)&bufA[(rt * 16 + lm) * SH + kb];
#pragma unroll
        for (int ct = 0; ct < 4; ++ct)
            bfr[ct] = *(const bf16x8*)&cw1T[(size_t)(w * 64 + ct * 16 + lm) * 256 + kb];
#pragma unroll
        for (int rt = 0; rt < 4; ++rt)
#pragma unroll
            for (int ct = 0; ct < 4; ++ct)
                acc3[rt][ct] = __builtin_amdgcn_mfma_f32_16x16x32_bf16(
                    a[rt], bfr[ct], acc3[rt][ct], 0, 0, 0);
    }
    {
        float cb[4], cwv[4];
#pragma unroll
        for (int ct = 0; ct < 4; ++ct) {
            const int col = w * 64 + ct * 16 + lm;
            cb[ct] = cb1[col]; cwv[ct] = cw2[col];
        }
#pragma unroll
        for (int rt = 0; rt < 4; ++rt)
#pragma unroll
            for (int reg = 0; reg < 4; ++reg) {
                float s = 0.f;
#pragma unroll
                for (int ct = 0; ct < 4; ++ct)
                    s += silu_f(acc3[rt][ct][reg] + cb[ct]) * cwv[ct];
#pragma unroll
                for (int m = 1; m <= 8; m <<= 1) s += __shfl_xor(s, m, 64);
                if (lm == 0) wpart[rt * 16 + quad * 4 + reg][w] = s;
            }
    }
    __syncthreads();

    // --- streaming outputs to CSR slots ---
    if (tid < TE) {
        float ww = wpart[tid][0] + wpart[tid][1] + wpart[tid][2] + wpart[tid][3];
        float4 o = { cd_s[tid][0] * ww, cd_s[tid][1] * ww, cd_s[tid][2] * ww, 0.f };
        wd[(size_t)b * EE + slot_s[tid]] = o;
    }
    for (int idx = tid; idx < TE * 32; idx += 256) {   // 32 x 16B per row
        const int e = idx >> 5, c = idx & 31;
        uint4 v = *(const uint4*)&bufA[e * SH + c * 8];
        *(uint4*)&efb[((size_t)b * EE + slot_s[e]) * HHdim + c * 8] = v;
    }
}

// ---------------------------------------------------------------------------
// fused gather + node MLP (MFMA bf16): one block = 32 nodes of one batch.
// ef rows are CSR-ordered -> per-node slot ranges are contiguous (streaming).
__global__ __launch_bounds__(256, 4)
void node_kernel(const float* __restrict__ h,
                 const float* __restrict__ coord,
                 const unsigned short* __restrict__ efb,
                 const float4* __restrict__ wd,
                 const int* __restrict__ offsets,
                 const unsigned short* __restrict__ nw1T, const float* __restrict__ nb1,
                 const unsigned short* __restrict__ nw2T, const float* __restrict__ nb2,
                 float* __restrict__ hout, float* __restrict__ coord_out) {
    __shared__ unsigned short bufN[NT * SA];   // [h|agg] bf16; then mid overlay (SM)

    const int tid = threadIdx.x;
    const int b = blockIdx.y;
    const int n0 = blockIdx.x * NT;
    const int lane = tid & 63;
    const int w = tid >> 6;
    const int lm = lane & 15;
    const int quad = lane >> 4;
    const int koff = quad * 8;

    // stage h rows (fp32 -> bf16), cols 0..127
    for (int idx = tid; idx < NT * 32; idx += 256) {
        const int r = idx >> 5, c4 = idx & 31;
        float4 v = *(const float4*)&h[((size_t)b * NN + n0 + r) * FFdim + c4 * 4];
        ushort4 u;
        u.x = f2bf(v.x); u.y = f2bf(v.y); u.z = f2bf(v.z); u.w = f2bf(v.w);
        *(ushort4*)&bufN[r * SA + c4 * 4] = u;
    }

    // gather: wave w handles nodes w*8 .. w*8+7
    for (int i = 0; i < 8; ++i) {
        const int r = w * 8 + i;
        const int n = n0 + r;
        const int o0 = offsets[n], o1 = offsets[n + 1];
        float a0 = 0.f, a1 = 0.f, a2 = 0.f, a3 = 0.f;
        const unsigned short* ebase = efb + (size_t)b * EE * HHdim + lane * 4;
        int j = o0;
        for (; j + 4 <= o1; j += 4) {
            ushort4 u0 = *(const ushort4*)(ebase + (size_t)(j + 0) * HHdim);
            ushort4 u1 = *(const ushort4*)(ebase + (size_t)(j + 1) * HHdim);
            ushort4 u2 = *(const ushort4*)(ebase + (size_t)(j + 2) * HHdim);
            ushort4 u3 = *(const ushort4*)(ebase + (size_t)(j + 3) * HHdim);
            a0 += bf2f(u0.x) + bf2f(u1.x) + bf2f(u2.x) + bf2f(u3.x);
            a1 += bf2f(u0.y) + bf2f(u1.y) + bf2f(u2.y) + bf2f(u3.y);
            a2 += bf2f(u0.z) + bf2f(u1.z) + bf2f(u2.z) + bf2f(u3.z);
            a3 += bf2f(u0.w) + bf2f(u1.w) + bf2f(u2.w) + bf2f(u3.w);
        }
        for (; j < o1; ++j) {
            ushort4 u = *(const ushort4*)(ebase + (size_t)j * HHdim);
            a0 += bf2f(u.x); a1 += bf2f(u.y); a2 += bf2f(u.z); a3 += bf2f(u.w);
        }
        ushort4 o;
        o.x = f2bf(a0); o.y = f2bf(a1); o.z = f2bf(a2); o.w = f2bf(a3);
        *(ushort4*)&bufN[r * SA + FFdim + lane * 4] = o;

        // coord_out = coord + sum(wd)
        float sx = 0.f, sy = 0.f, sz = 0.f;
        for (int jj = o0 + lane; jj < o1; jj += 64) {
            float4 t = wd[(size_t)b * EE + jj];
            sx += t.x; sy += t.y; sz += t.z;
        }
#pragma unroll
        for (int m = 1; m < 64; m <<= 1) {
            sx += __shfl_xor(sx, m, 64);
            sy += __shfl_xor(sy, m, 64);
            sz += __shfl_xor(sz, m, 64);
        }
        if (lane < 3) {
            const size_t cb = ((size_t)b * NN + n) * 3 + lane;
            float s = (lane == 0) ? sx : (lane == 1) ? sy : sz;
            coord_out[cb] = coord[cb] + s;
        }
    }
    __syncthreads();

    // GEMM-A: [h|agg][32 x 384] @ nw1T[256 x 384] -> mid[32 x 256], silu
    floatx4 acc[2][4];
#pragma unroll
    for (int i = 0; i < 2; ++i)
#pragma unroll
        for (int j = 0; j < 4; ++j)
#pragma unroll
            for (int q = 0; q < 4; ++q) acc[i][j][q] = 0.f;
#pragma unroll
    for (int ks = 0; ks < 12; ++ks) {
        const int kb = ks * 32 + koff;
        bf16x8 a[2], bfr[4];
#pragma unroll
        for (int rt = 0; rt < 2; ++rt)
            a[rt] = *(const bf16x8*)&bufN[(rt * 16 + lm) * SA + kb];
#pragma unroll
        for (int ct = 0; ct < 4; ++ct)
            bfr[ct] = *(const bf16x8*)&nw1T[(size_t)(w * 64 + ct * 16 + lm) * 384 + kb];
#pragma unroll
        for (int rt = 0; rt < 2; ++rt)
#pragma unroll
            for (int ct = 0; ct < 4; ++ct)
                acc[rt][ct] = __builtin_amdgcn_mfma_f32_16x16x32_bf16(
                    a[rt], bfr[ct], acc[rt][ct], 0, 0, 0);
    }
    __syncthreads();   // A dead; overlay mid (stride SM)
#pragma unroll
    for (int ct = 0; ct < 4; ++ct) {
        const int col = w * 64 + ct * 16 + lm;
        const float bias = nb1[col];
#pragma unroll
        for (int rt = 0; rt < 2; ++rt)
#pragma unroll
            for (int reg = 0; reg < 4; ++reg) {
                const int row = rt * 16 + quad * 4 + reg;
                bufN[row * SM + col] = f2bf(silu_f(acc[rt][ct][reg] + bias));
            }
    }
    __syncthreads();

    // GEMM-B: mid[32 x 256] @ nw2T[128 x 256] -> out[32 x 128] + bias + residual
    floatx4 accb[2][2];
#pragma unroll
    for (int i = 0; i < 2; ++i)
#pragma unroll
        for (int j = 0; j < 2; ++j)
#pragma unroll
            for (int q = 0; q < 4; ++q) accb[i][j][q] = 0.f;
#pragma unroll
    for (int ks = 0; ks < 8; ++ks) {
        const int kb = ks * 32 + koff;
        bf16x8 a[2], bfr[2];
#pragma unroll
        for (int rt = 0; rt < 2; ++rt)
            a[rt] = *(const bf16x8*)&bufN[(rt * 16 + lm) * SM + kb];
#pragma unroll
        for (int ct = 0; ct < 2; ++ct)
            bfr[ct] = *(const bf16x8*)&nw2T[(size_t)(w * 32 + ct * 16 + lm) * 256 + kb];
#pragma unroll
        for (int rt = 0; rt < 2; ++rt)
#pragma unroll
            for (int ct = 0; ct < 2; ++ct)
                accb[rt][ct] = __builtin_amdgcn_mfma_f32_16x16x32_bf16(
                    a[rt], bfr[ct], accb[rt][ct], 0, 0, 0);
    }
#pragma unroll
    for (int ct = 0; ct < 2; ++ct) {
        const int col = w * 32 + ct * 16 + lm;
        const float bias = nb2[col];
#pragma unroll
        for (int rt = 0; rt < 2; ++rt)
#pragma unroll
            for (int reg = 0; reg < 4; ++reg) {
                const int row = rt * 16 + quad * 4 + reg;
                const size_t gi = ((size_t)b * NN + n0 + row) * FFdim + col;
                hout[gi] = accb[rt][ct][reg] + bias + h[gi];
            }
    }
}

// ---------------------------------------------------------------------------
extern "C" void kernel_launch(void* const* d_in, const int* in_sizes, int n_in,
                              void* d_out, int out_size, void* d_ws, size_t ws_size,
                              hipStream_t stream) {
    const float* h     = (const float*)d_in[0];
    const float* coord = (const float*)d_in[1];
    const int*   eidx  = (const int*)d_in[2];
    const float* w1    = (const float*)d_in[3];
    const float* b1    = (const float*)d_in[4];
    const float* w2    = (const float*)d_in[5];
    const float* b2    = (const float*)d_in[6];
    const float* lng   = (const float*)d_in[7];
    const float* lnb   = (const float*)d_in[8];
    const float* nw1   = (const float*)d_in[9];
    const float* nb1   = (const float*)d_in[10];
    const float* nw2   = (const float*)d_in[11];
    const float* nb2   = (const float*)d_in[12];
    const float* cw1   = (const float*)d_in[13];
    const float* cb1   = (const float*)d_in[14];
    const float* cw2   = (const float*)d_in[15];

    float* hout = (float*)d_out;
    float* coord_out = hout + (size_t)BB * NN * FFdim;

    char* p = (char*)d_ws;
    float4* wd = (float4*)p;                   p += (size_t)BB * EE * 16;          // 4 MB
    unsigned short* efb = (unsigned short*)p;  p += (size_t)BB * EE * HHdim * 2;   // 134 MB
    unsigned short* w1T = (unsigned short*)p;  p += (size_t)W1T_ELEMS * 2;
    unsigned short* w2T = (unsigned short*)p;  p += (size_t)W2T_ELEMS * 2;
    unsigned short* cw1T = (unsigned short*)p; p += (size_t)CW1T_ELEMS * 2;
    unsigned short* nw1T = (unsigned short*)p; p += (size_t)NW1T_ELEMS * 2;
    unsigned short* nw2T = (unsigned short*)p; p += (size_t)NW2T_ELEMS * 2;
    int* counts = (int*)p;                     p += (size_t)NN * 4;
    int* offsets = (int*)p;                    p += (size_t)(NN + 1) * 4;
    int* cursor = (int*)p;                     p += (size_t)NN * 4;
    int* perm = (int*)p;                       p += (size_t)EE * 4;

    hipLaunchKernelGGL(prep_weights, dim3((WT_E + NN) / 256), dim3(256),
                       0, stream, w1, w2, cw1, nw1, nw2,
                       w1T, w2T, cw1T, nw1T, nw2T, counts);
    hipLaunchKernelGGL(csr_count, dim3(EE / 256), dim3(256), 0, stream, eidx, counts);
    hipLaunchKernelGGL(csr_scan, dim3(1), dim3(256), 0, stream, counts, offsets, cursor);
    hipLaunchKernelGGL(csr_fill, dim3(EE / 256), dim3(256), 0, stream, eidx, cursor, perm);
    hipLaunchKernelGGL(edge_kernel, dim3(EE / TE, BB), dim3(256), 0, stream,
                       h, coord, eidx, perm, w1T, b1, w2T, b2, lng, lnb, cw1T, cb1, cw2,
                       efb, wd);
    hipLaunchKernelGGL(node_kernel, dim3(NN / NT, BB), dim3(256), 0, stream,
                       h, coord, efb, wd, offsets, nw1T, nb1, nw2T, nb2,
                       hout, coord_out);
}

// Round 5
// 362.780 us; speedup vs baseline: 3.1443x; 1.0090x over previous
//
#include <hip/hip_runtime.h>
#include <cstdint>
#include <cstddef>

#define BB 2
#define NN 8192
#define EE 131072
#define FFdim 128
#define HHdim 256
#define NHEAD 4
#define DHEAD 64
#define FEATD 268
#define K1PAD 288        // FEAT padded to multiple of 32
#define SF 296           // feat LDS row stride (ushort); 592B: 2-way bank alias, free
#define SH 264           // hmid/ef overlay stride (ushort); 528B, 16B-aligned, 2-way free
#define TE 64            // edges per edge-block
#define NT 32            // nodes per node-block
#define SA 392           // node A ([h|agg], 384) stride (ushort); 784B, 2-way free
#define SM 264           // node mid overlay stride (ushort)

typedef short bf16x8 __attribute__((ext_vector_type(8)));
typedef float floatx4 __attribute__((ext_vector_type(4)));

__device__ __forceinline__ float silu_f(float x) {
    // v_rcp instead of IEEE div sequence: ~1ulp, way inside bf16 tolerance
    return x * __fdividef(1.0f, 1.0f + __expf(-x));
}
__device__ __forceinline__ unsigned short f2bf(float x) {
    unsigned int u = __float_as_uint(x);
    unsigned int r = (u + 0x7fffu + ((u >> 16) & 1u)) >> 16;
    return (unsigned short)r;
}
__device__ __forceinline__ float bf2f(unsigned short u) {
    return __uint_as_float(((unsigned int)u) << 16);
}
// permuted within-64 position p -> original offset (p = lm*4+ct, o = ct*16+lm)
__device__ __forceinline__ int operm(int p) { return ((p & 3) << 4) | (p >> 2); }

// ---------------------------------------------------------------------------
// prep: fp32 weights -> transposed (and k-permuted) bf16 layouts; zero counts.
#define W1T_ELEMS (256 * K1PAD)
#define W2T_ELEMS (256 * 64)
#define CW1T_ELEMS (256 * 256)
#define NW1T_ELEMS (256 * 384)
#define NW2T_ELEMS (128 * 256)
#define WT_A (W1T_ELEMS)
#define WT_B (W1T_ELEMS + W2T_ELEMS)
#define WT_C (W1T_ELEMS + W2T_ELEMS + CW1T_ELEMS)
#define WT_D (WT_C + NW1T_ELEMS)
#define WT_E (WT_D + NW2T_ELEMS)
__global__ void prep_weights(const float* __restrict__ w1,
                             const float* __restrict__ w2,
                             const float* __restrict__ cw1,
                             const float* __restrict__ nw1,
                             const float* __restrict__ nw2,
                             unsigned short* __restrict__ w1T,
                             unsigned short* __restrict__ w2T,
                             unsigned short* __restrict__ cw1T,
                             unsigned short* __restrict__ nw1T,
                             unsigned short* __restrict__ nw2T,
                             int* __restrict__ counts) {
    int idx = blockIdx.x * blockDim.x + threadIdx.x;
    if (idx < WT_A) {
        int n = idx / K1PAD, k = idx % K1PAD;
        int hh = n >> 6, d = n & 63;
        float v = (k < FEATD) ? w1[((size_t)hh * FEATD + k) * DHEAD + d] : 0.f;
        w1T[idx] = f2bf(v);
    } else if (idx < WT_B) {
        int j = idx - WT_A;
        int n = j >> 6, p = j & 63;
        int hh = n >> 6, dout = n & 63;
        int din = operm(p);
        w2T[j] = f2bf(w2[(size_t)hh * 4096 + din * 64 + dout]);
    } else if (idx < WT_C) {
        int j = idx - WT_B;
        int n = j >> 8, P = j & 255;
        int ko = (P >> 6) * 64 + operm(P & 63);
        cw1T[j] = f2bf(cw1[ko * 256 + n]);
    } else if (idx < WT_D) {
        int j = idx - WT_C;
        int n = j / 384, k = j % 384;
        int ko = (k < 128) ? k : 128 + ((k - 128) >> 6) * 64 + operm(k & 63);
        nw1T[j] = f2bf(nw1[ko * 256 + n]);
    } else if (idx < WT_E) {
        int j = idx - WT_D;
        int n = j >> 8, P = j & 255;
        int ko = (P >> 6) * 64 + operm(P & 63);
        nw2T[j] = f2bf(nw2[ko * 128 + n]);
    } else if (idx < WT_E + NN) {
        counts[idx - WT_E] = 0;
    }
}

// ---------------------------------------------------------------------------
// CSR build (row indices shared across batches)
__global__ void csr_count(const int* __restrict__ eidx, int* __restrict__ counts) {
    int e = blockIdx.x * 256 + threadIdx.x;
    atomicAdd(&counts[eidx[e]], 1);
}

__global__ void csr_scan(const int* __restrict__ counts,
                         int* __restrict__ offsets,
                         int* __restrict__ cursor) {
    __shared__ int wsum[4];
    const int t = threadIdx.x;
    const int base = t * 32;
    int local[32];
    int s = 0;
#pragma unroll
    for (int i = 0; i < 32; ++i) { local[i] = counts[base + i]; s += local[i]; }
    const int lane = t & 63, w = t >> 6;
    int v = s;
#pragma unroll
    for (int off = 1; off < 64; off <<= 1) {
        int u = __shfl_up(v, off, 64);
        if (lane >= off) v += u;
    }
    if (lane == 63) wsum[w] = v;
    __syncthreads();
    int wbase = 0;
    for (int i = 0; i < w; ++i) wbase += wsum[i];
    int run = wbase + v - s;
#pragma unroll
    for (int i = 0; i < 32; ++i) {
        offsets[base + i] = run;
        cursor[base + i] = run;
        run += local[i];
    }
    if (t == 255) offsets[NN] = run;
}

__global__ void csr_fill(const int* __restrict__ eidx,
                         int* __restrict__ cursor, int* __restrict__ perm) {
    int e = blockIdx.x * 256 + threadIdx.x;
    int r = eidx[e];
    int pos = atomicAdd(&cursor[r], 1);
    perm[e] = pos;
}

// ---------------------------------------------------------------------------
// edge kernel (MFMA bf16): one block = 64 edges of one batch, 256 threads.
// LDS hmid/ef columns stored pi-permuted within each 64-col head block
// (pos = lm*4+ct); all consumer weights are k-permuted to match in prep.
__global__ __launch_bounds__(256, 3)
void edge_kernel(const float* __restrict__ h,
                 const float* __restrict__ coord,
                 const int* __restrict__ eidx,
                 const int* __restrict__ perm,
                 const unsigned short* __restrict__ w1T, const float* __restrict__ b1,
                 const unsigned short* __restrict__ w2T, const float* __restrict__ b2,
                 const float* __restrict__ lng, const float* __restrict__ lnb,
                 const unsigned short* __restrict__ cw1T, const float* __restrict__ cb1,
                 const float* __restrict__ cw2,
                 unsigned short* __restrict__ efb, float4* __restrict__ wd) {
    __shared__ unsigned short bufA[TE * SF];   // feat; then hmid/ef overlay (stride SH)
    __shared__ int slot_s[TE];
    __shared__ float cd_s[TE][3];
    __shared__ float2 lnred[TE][4];
    __shared__ float mu_s[TE], rs_s[TE];
    __shared__ float wpart[TE][4];

    const int tid = threadIdx.x;
    const int b = blockIdx.y;
    const int e0 = blockIdx.x * TE;
    const int lane = tid & 63;
    const int w = tid >> 6;          // wave id = column quarter / head
    const int lm = lane & 15;
    const int quad = lane >> 4;
    const int koff = quad * 8;

    // --- phase 1: geometry + slot (one thread per edge) ---
    if (tid < TE) {
        const int e = e0 + tid;
        const int r = eidx[e], c = eidx[EE + e];
        slot_s[tid] = perm[e];
        const float* pi = coord + ((size_t)b * NN + r) * 3;
        const float* pk = coord + ((size_t)b * NN + c) * 3;
        float ci0 = pi[0], ci1 = pi[1], ci2 = pi[2];
        float ck0 = pk[0], ck1 = pk[1], ck2 = pk[2];
        float dx = ci0 - ck0, dy = ci1 - ck1, dz = ci2 - ck2;
        float radial = dx * dx + dy * dy + dz * dz;
        float dist = sqrtf(radial);
        float dotv = ci0 * ck0 + ci1 * ck1 + ci2 * ck2;
        float inva = __fdividef(1.0f, dist + 1e-8f);
        float a0 = dx * inva, a1 = dy * inva, a2 = dz * inva;
        float cr0 = ci1 * ck2 - ci2 * ck1;
        float cr1 = ci2 * ck0 - ci0 * ck2;
        float cr2 = ci0 * ck1 - ci1 * ck0;
        float nb = sqrtf(cr0 * cr0 + cr1 * cr1 + cr2 * cr2);
        float invb = __fdividef(1.0f, nb + 1e-8f);
        float b0 = cr0 * invb, b1v = cr1 * invb, b2v = cr2 * invb;
        float c0 = a1 * b2v - a2 * b1v;
        float c1 = a2 * b0 - a0 * b2v;
        float c2 = a0 * b1v - a1 * b0;
        float na = sqrtf(a0 * a0 + a1 * a1 + a2 * a2);
        float nbn = sqrtf(b0 * b0 + b1v * b1v + b2v * b2v);
        float nc = sqrtf(c0 * c0 + c1 * c1 + c2 * c2);
        bool bad = (na < 1e-6f) || (nbn < 1e-6f) || (nc < 1e-6f);
        float s[12];
        s[0] = radial; s[1] = dist; s[2] = dotv;
        if (bad) {
            s[3] = 1.f; s[4] = 0.f; s[5] = 0.f;
            s[6] = 0.f; s[7] = 1.f; s[8] = 0.f;
            s[9] = 0.f; s[10] = 0.f; s[11] = 1.f;
        } else {
            s[3] = a0;  s[4] = b0;  s[5] = c0;
            s[6] = a1;  s[7] = b1v; s[8] = c1;
            s[9] = a2;  s[10] = b2v; s[11] = c2;
        }
        unsigned short* fp = &bufA[tid * SF];
#pragma unroll
        for (int q = 0; q < 12; ++q) fp[256 + q] = f2bf(s[q]);
#pragma unroll
        for (int q = FEATD; q < K1PAD; ++q) fp[q] = 0;
        cd_s[tid][0] = dx; cd_s[tid][1] = dy; cd_s[tid][2] = dz;
    }
    // --- phase 2: gather h[row], h[col] -> bf16 feat ---
    for (int idx = tid; idx < TE * 64; idx += 256) {
        const int e = idx >> 6, c4 = idx & 63;
        const int node = (c4 < 32) ? eidx[e0 + e] : eidx[EE + e0 + e];
        const int cc = (c4 < 32) ? c4 * 4 : (c4 - 32) * 4;
        float4 v = *(const float4*)&h[((size_t)b * NN + node) * FFdim + cc];
        ushort4 u;
        u.x = f2bf(v.x); u.y = f2bf(v.y); u.z = f2bf(v.z); u.w = f2bf(v.w);
        *(ushort4*)&bufA[e * SF + c4 * 4] = u;
    }
    __syncthreads();

    // --- GEMM1: feat[64 x 288] @ w1T -> hmid[64 x 256], silu ---
    floatx4 acc[4][4];
#pragma unroll
    for (int i = 0; i < 4; ++i)
#pragma unroll
        for (int j = 0; j < 4; ++j)
#pragma unroll
            for (int q = 0; q < 4; ++q) acc[i][j][q] = 0.f;
#pragma unroll
    for (int ks = 0; ks < K1PAD / 32; ++ks) {
        const int kb = ks * 32 + koff;
        bf16x8 a[4], bfr[4];
#pragma unroll
        for (int rt = 0; rt < 4; ++rt)
            a[rt] = *(const bf16x8*)&bufA[(rt * 16 + lm) * SF + kb];
#pragma unroll
        for (int ct = 0; ct < 4; ++ct)
            bfr[ct] = *(const bf16x8*)&w1T[(size_t)(w * 64 + ct * 16 + lm) * K1PAD + kb];
#pragma unroll
        for (int rt = 0; rt < 4; ++rt)
#pragma unroll
            for (int ct = 0; ct < 4; ++ct)
                acc[rt][ct] = __builtin_amdgcn_mfma_f32_16x16x32_bf16(
                    a[rt], bfr[ct], acc[rt][ct], 0, 0, 0);
    }
    float bias1[4];
#pragma unroll
    for (int ct = 0; ct < 4; ++ct) bias1[ct] = b1[w * 64 + ct * 16 + lm];
    __syncthreads();   // feat dead; bufA becomes hmid/ef (stride SH, pi-permuted)
#pragma unroll
    for (int rt = 0; rt < 4; ++rt)
#pragma unroll
        for (int reg = 0; reg < 4; ++reg) {
            const int row = rt * 16 + quad * 4 + reg;
            ushort4 pk;
            pk.x = f2bf(silu_f(acc[rt][0][reg] + bias1[0]));
            pk.y = f2bf(silu_f(acc[rt][1][reg] + bias1[1]));
            pk.z = f2bf(silu_f(acc[rt][2][reg] + bias1[2]));
            pk.w = f2bf(silu_f(acc[rt][3][reg] + bias1[3]));
            *(ushort4*)&bufA[row * SH + w * 64 + lm * 4] = pk;
        }
    // wave-local: wave w's GEMM2 reads only the quarter wave w wrote.

    // --- GEMM2: hmid[:, head w] @ w2T(head w) ---
    floatx4 acc2[4][4];
#pragma unroll
    for (int i = 0; i < 4; ++i)
#pragma unroll
        for (int j = 0; j < 4; ++j)
#pragma unroll
            for (int q = 0; q < 4; ++q) acc2[i][j][q] = 0.f;
#pragma unroll
    for (int ks = 0; ks < 2; ++ks) {
        const int kb = ks * 32 + koff;
        bf16x8 a[4], bfr[4];
#pragma unroll
        for (int rt = 0; rt < 4; ++rt)
            a[rt] = *(const bf16x8*)&bufA[(rt * 16 + lm) * SH + w * 64 + kb];
#pragma unroll
        for (int ct = 0; ct < 4; ++ct)
            bfr[ct] = *(const bf16x8*)&w2T[(size_t)(w * 64 + ct * 16 + lm) * 64 + kb];
#pragma unroll
        for (int rt = 0; rt < 4; ++rt)
#pragma unroll
            for (int ct = 0; ct < 4; ++ct)
                acc2[rt][ct] = __builtin_amdgcn_mfma_f32_16x16x32_bf16(
                    a[rt], bfr[ct], acc2[rt][ct], 0, 0, 0);
    }
    // --- bias + LayerNorm ---
    float bias2[4];
#pragma unroll
    for (int ct = 0; ct < 4; ++ct) bias2[ct] = b2[w * 64 + ct * 16 + lm];
#pragma unroll
    for (int rt = 0; rt < 4; ++rt)
#pragma unroll
        for (int reg = 0; reg < 4; ++reg) {
            float s = 0.f, s2 = 0.f;
#pragma unroll
            for (int ct = 0; ct < 4; ++ct) {
                float v = acc2[rt][ct][reg] + bias2[ct];
                acc2[rt][ct][reg] = v;
                s += v; s2 += v * v;
            }
#pragma unroll
            for (int m = 1; m <= 8; m <<= 1) {
                s += __shfl_xor(s, m, 64);
                s2 += __shfl_xor(s2, m, 64);
            }
            if (lm == 0) {
                const int row = rt * 16 + quad * 4 + reg;
                lnred[row][w] = make_float2(s, s2);
            }
        }
    __syncthreads();
    if (tid < TE) {
        float s = 0.f, s2 = 0.f;
#pragma unroll
        for (int ww = 0; ww < 4; ++ww) { s += lnred[tid][ww].x; s2 += lnred[tid][ww].y; }
        float mean = s * (1.0f / 256.0f);
        float var = s2 * (1.0f / 256.0f) - mean * mean;
        mu_s[tid] = mean;
        rs_s[tid] = rsqrtf(var + 1e-5f);
    }
    __syncthreads();
    {
        float gv[4], bv[4];
#pragma unroll
        for (int ct = 0; ct < 4; ++ct) {
            const int col = w * 64 + ct * 16 + lm;
            gv[ct] = lng[col]; bv[ct] = lnb[col];
        }
#pragma unroll
        for (int rt = 0; rt < 4; ++rt)
#pragma unroll
            for (int reg = 0; reg < 4; ++reg) {
                const int row = rt * 16 + quad * 4 + reg;
                const float mu = mu_s[row], rs = rs_s[row];
                ushort4 pk;
                pk.x = f2bf((acc2[rt][0][reg] - mu) * rs * gv[0] + bv[0]);
                pk.y = f2bf((acc2[rt][1][reg] - mu) * rs * gv[1] + bv[1]);
                pk.z = f2bf((acc2[rt][2][reg] - mu) * rs * gv[2] + bv[2]);
                pk.w = f2bf((acc2[rt][3][reg] - mu) * rs * gv[3] + bv[3]);
                *(ushort4*)&bufA[row * SH + w * 64 + lm * 4] = pk;
            }
    }
    __syncthreads();

    // --- GEMM3: ef[64 x 256] @ cw1T -> silu -> dot cw2 -> w per edge ---
    floatx4 acc3[4][4];
#pragma unroll
    for (int i = 0; i < 4; ++i)
#pragma unroll
        for (int j = 0; j < 4; ++j)
#pragma unroll
            for (int q = 0; q < 4; ++q) acc3[i][j][q] = 0.f;
#pragma unroll
    for (int ks = 0; ks < 8; ++ks) {
        const int kb = ks * 32 + koff;
        bf16x8 a[4], bfr[4];
#pragma unroll
        for (int rt = 0; rt < 4; ++rt)
            a[rt] = *(const bf16x8*)&bufA[(rt * 16 + lm) * SH + kb];
#pragma unroll
        for (int ct = 0; ct < 4; ++ct)
            bfr[ct] = *(const bf16x8*)&cw1T[(size_t)(w * 64 + ct * 16 + lm) * 256 + kb];
#pragma unroll
        for (int rt = 0; rt < 4; ++rt)
#pragma unroll
            for (int ct = 0; ct < 4; ++ct)
                acc3[rt][ct] = __builtin_amdgcn_mfma_f32_16x16x32_bf16(
                    a[rt], bfr[ct], acc3[rt][ct], 0, 0, 0);
    }
    {
        float cb[4], cwv[4];
#pragma unroll
        for (int ct = 0; ct < 4; ++ct) {
            const int col = w * 64 + ct * 16 + lm;
            cb[ct] = cb1[col]; cwv[ct] = cw2[col];
        }
#pragma unroll
        for (int rt = 0; rt < 4; ++rt)
#pragma unroll
            for (int reg = 0; reg < 4; ++reg) {
                float s = 0.f;
#pragma unroll
                for (int ct = 0; ct < 4; ++ct)
                    s += silu_f(acc3[rt][ct][reg] + cb[ct]) * cwv[ct];
#pragma unroll
                for (int m = 1; m <= 8; m <<= 1) s += __shfl_xor(s, m, 64);
                if (lm == 0) wpart[rt * 16 + quad * 4 + reg][w] = s;
            }
    }
    __syncthreads();

    // --- streaming outputs to CSR slots ---
    if (tid < TE) {
        float ww = wpart[tid][0] + wpart[tid][1] + wpart[tid][2] + wpart[tid][3];
        float4 o = { cd_s[tid][0] * ww, cd_s[tid][1] * ww, cd_s[tid][2] * ww, 0.f };
        wd[(size_t)b * EE + slot_s[tid]] = o;
    }
    for (int idx = tid; idx < TE * 32; idx += 256) {   // 32 x 16B per row
        const int e = idx >> 5, c = idx & 31;
        uint4 v = *(const uint4*)&bufA[e * SH + c * 8];
        *(uint4*)&efb[((size_t)b * EE + slot_s[e]) * HHdim + c * 8] = v;
    }
}

// ---------------------------------------------------------------------------
// fused gather + node MLP (MFMA bf16): one block = 32 nodes of one batch.
__global__ __launch_bounds__(256, 4)
void node_kernel(const float* __restrict__ h,
                 const float* __restrict__ coord,
                 const unsigned short* __restrict__ efb,
                 const float4* __restrict__ wd,
                 const int* __restrict__ offsets,
                 const unsigned short* __restrict__ nw1T, const float* __restrict__ nb1,
                 const unsigned short* __restrict__ nw2T, const float* __restrict__ nb2,
                 float* __restrict__ hout, float* __restrict__ coord_out) {
    __shared__ unsigned short bufN[NT * SA];   // [h|agg] bf16; then mid overlay (SM)

    const int tid = threadIdx.x;
    const int b = blockIdx.y;
    const int n0 = blockIdx.x * NT;
    const int lane = tid & 63;
    const int w = tid >> 6;
    const int lm = lane & 15;
    const int quad = lane >> 4;
    const int koff = quad * 8;

    // stage h rows (fp32 -> bf16), cols 0..127
    for (int idx = tid; idx < NT * 32; idx += 256) {
        const int r = idx >> 5, c4 = idx & 31;
        float4 v = *(const float4*)&h[((size_t)b * NN + n0 + r) * FFdim + c4 * 4];
        ushort4 u;
        u.x = f2bf(v.x); u.y = f2bf(v.y); u.z = f2bf(v.z); u.w = f2bf(v.w);
        *(ushort4*)&bufN[r * SA + c4 * 4] = u;
    }

    // gather: wave w handles nodes w*8 .. w*8+7 (slot ranges contiguous)
    for (int i = 0; i < 8; ++i) {
        const int r = w * 8 + i;
        const int n = n0 + r;
        const int o0 = offsets[n], o1 = offsets[n + 1];
        float a0 = 0.f, a1 = 0.f, a2 = 0.f, a3 = 0.f;
        const unsigned short* ebase = efb + (size_t)b * EE * HHdim + lane * 4;
        int j = o0;
        for (; j + 4 <= o1; j += 4) {
            ushort4 u0 = *(const ushort4*)(ebase + (size_t)(j + 0) * HHdim);
            ushort4 u1 = *(const ushort4*)(ebase + (size_t)(j + 1) * HHdim);
            ushort4 u2 = *(const ushort4*)(ebase + (size_t)(j + 2) * HHdim);
            ushort4 u3 = *(const ushort4*)(ebase + (size_t)(j + 3) * HHdim);
            a0 += bf2f(u0.x) + bf2f(u1.x) + bf2f(u2.x) + bf2f(u3.x);
            a1 += bf2f(u0.y) + bf2f(u1.y) + bf2f(u2.y) + bf2f(u3.y);
            a2 += bf2f(u0.z) + bf2f(u1.z) + bf2f(u2.z) + bf2f(u3.z);
            a3 += bf2f(u0.w) + bf2f(u1.w) + bf2f(u2.w) + bf2f(u3.w);
        }
        for (; j < o1; ++j) {
            ushort4 u = *(const ushort4*)(ebase + (size_t)j * HHdim);
            a0 += bf2f(u.x); a1 += bf2f(u.y); a2 += bf2f(u.z); a3 += bf2f(u.w);
        }
        ushort4 o;
        o.x = f2bf(a0); o.y = f2bf(a1); o.z = f2bf(a2); o.w = f2bf(a3);
        *(ushort4*)&bufN[r * SA + FFdim + lane * 4] = o;

        // coord_out = coord + sum(wd)
        float sx = 0.f, sy = 0.f, sz = 0.f;
        for (int jj = o0 + lane; jj < o1; jj += 64) {
            float4 t = wd[(size_t)b * EE + jj];
            sx += t.x; sy += t.y; sz += t.z;
        }
#pragma unroll
        for (int m = 1; m < 64; m <<= 1) {
            sx += __shfl_xor(sx, m, 64);
            sy += __shfl_xor(sy, m, 64);
            sz += __shfl_xor(sz, m, 64);
        }
        if (lane < 3) {
            const size_t cb = ((size_t)b * NN + n) * 3 + lane;
            float s = (lane == 0) ? sx : (lane == 1) ? sy : sz;
            coord_out[cb] = coord[cb] + s;
        }
    }
    __syncthreads();

    // GEMM-A: [h|agg][32 x 384] @ nw1T -> mid[32 x 256], silu (pi-packed store)
    floatx4 acc[2][4];
#pragma unroll
    for (int i = 0; i < 2; ++i)
#pragma unroll
        for (int j = 0; j < 4; ++j)
#pragma unroll
            for (int q = 0; q < 4; ++q) acc[i][j][q] = 0.f;
#pragma unroll
    for (int ks = 0; ks < 12; ++ks) {
        const int kb = ks * 32 + koff;
        bf16x8 a[2], bfr[4];
#pragma unroll
        for (int rt = 0; rt < 2; ++rt)
            a[rt] = *(const bf16x8*)&bufN[(rt * 16 + lm) * SA + kb];
#pragma unroll
        for (int ct = 0; ct < 4; ++ct)
            bfr[ct] = *(const bf16x8*)&nw1T[(size_t)(w * 64 + ct * 16 + lm) * 384 + kb];
#pragma unroll
        for (int rt = 0; rt < 2; ++rt)
#pragma unroll
            for (int ct = 0; ct < 4; ++ct)
                acc[rt][ct] = __builtin_amdgcn_mfma_f32_16x16x32_bf16(
                    a[rt], bfr[ct], acc[rt][ct], 0, 0, 0);
    }
    float nb1v[4];
#pragma unroll
    for (int ct = 0; ct < 4; ++ct) nb1v[ct] = nb1[w * 64 + ct * 16 + lm];
    __syncthreads();   // A dead; overlay mid (stride SM, pi-permuted)
#pragma unroll
    for (int rt = 0; rt < 2; ++rt)
#pragma unroll
        for (int reg = 0; reg < 4; ++reg) {
            const int row = rt * 16 + quad * 4 + reg;
            ushort4 pk;
            pk.x = f2bf(silu_f(acc[rt][0][reg] + nb1v[0]));
            pk.y = f2bf(silu_f(acc[rt][1][reg] + nb1v[1]));
            pk.z = f2bf(silu_f(acc[rt][2][reg] + nb1v[2]));
            pk.w = f2bf(silu_f(acc[rt][3][reg] + nb1v[3]));
            *(ushort4*)&bufN[row * SM + w * 64 + lm * 4] = pk;
        }
    __syncthreads();

    // GEMM-B: mid[32 x 256] @ nw2T -> out[32 x 128] + bias + residual
    floatx4 accb[2][2];
#pragma unroll
    for (int i = 0; i < 2; ++i)
#pragma unroll
        for (int j = 0; j < 2; ++j)
#pragma unroll
            for (int q = 0; q < 4; ++q) accb[i][j][q] = 0.f;
#pragma unroll
    for (int ks = 0; ks < 8; ++ks) {
        const int kb = ks * 32 + koff;
        bf16x8 a[2], bfr[2];
#pragma unroll
        for (int rt = 0; rt < 2; ++rt)
            a[rt] = *(const bf16x8*)&bufN[(rt * 16 + lm) * SM + kb];
#pragma unroll
        for (int ct = 0; ct < 2; ++ct)
            bfr[ct] = *(const bf16x8*)&nw2T[(size_t)(w * 32 + ct * 16 + lm) * 256 + kb];
#pragma unroll
        for (int rt = 0; rt < 2; ++rt)
#pragma unroll
            for (int ct = 0; ct < 2; ++ct)
                accb[rt][ct] = __builtin_amdgcn_mfma_f32_16x16x32_bf16(
                    a[rt], bfr[ct], accb[rt][ct], 0, 0, 0);
    }
#pragma unroll
    for (int ct = 0; ct < 2; ++ct) {
        const int col = w * 32 + ct * 16 + lm;
        const float bias = nb2[col];
#pragma unroll
        for (int rt = 0; rt < 2; ++rt)
#pragma unroll
            for (int reg = 0; reg < 4; ++reg) {
                const int row = rt * 16 + quad * 4 + reg;
                const size_t gi = ((size_t)b * NN + n0 + row) * FFdim + col;
                hout[gi] = accb[rt][ct][reg] + bias + h[gi];
            }
    }
}

// ---------------------------------------------------------------------------
extern "C" void kernel_launch(void* const* d_in, const int* in_sizes, int n_in,
                              void* d_out, int out_size, void* d_ws, size_t ws_size,
                              hipStream_t stream) {
    const float* h     = (const float*)d_in[0];
    const float* coord = (const float*)d_in[1];
    const int*   eidx  = (const int*)d_in[2];
    const float* w1    = (const float*)d_in[3];
    const float* b1    = (const float*)d_in[4];
    const float* w2    = (const float*)d_in[5];
    const float* b2    = (const float*)d_in[6];
    const float* lng   = (const float*)d_in[7];
    const float* lnb   = (const float*)d_in[8];
    const float* nw1   = (const float*)d_in[9];
    const float* nb1   = (const float*)d_in[10];
    const float* nw2   = (const float*)d_in[11];
    const float* nb2   = (const float*)d_in[12];
    const float* cw1   = (const float*)d_in[13];
    const float* cb1   = (const float*)d_in[14];
    const float* cw2   = (const float*)d_in[15];

    float* hout = (float*)d_out;
    float* coord_out = hout + (size_t)BB * NN * FFdim;

    char* p = (char*)d_ws;
    float4* wd = (float4*)p;                   p += (size_t)BB * EE * 16;          // 4 MB
    unsigned short* efb = (unsigned short*)p;  p += (size_t)BB * EE * HHdim * 2;   // 134 MB
    unsigned short* w1T = (unsigned short*)p;  p += (size_t)W1T_ELEMS * 2;
    unsigned short* w2T = (unsigned short*)p;  p += (size_t)W2T_ELEMS * 2;
    unsigned short* cw1T = (unsigned short*)p; p += (size_t)CW1T_ELEMS * 2;
    unsigned short* nw1T = (unsigned short*)p; p += (size_t)NW1T_ELEMS * 2;
    unsigned short* nw2T = (unsigned short*)p; p += (size_t)NW2T_ELEMS * 2;
    int* counts = (int*)p;                     p += (size_t)NN * 4;
    int* offsets = (int*)p;                    p += (size_t)(NN + 1) * 4;
    int* cursor = (int*)p;                     p += (size_t)NN * 4;
    int* perm = (int*)p;                       p += (size_t)EE * 4;

    hipLaunchKernelGGL(prep_weights, dim3((WT_E + NN) / 256), dim3(256),
                       0, stream, w1, w2, cw1, nw1, nw2,
                       w1T, w2T, cw1T, nw1T, nw2T, counts);
    hipLaunchKernelGGL(csr_count, dim3(EE / 256), dim3(256), 0, stream, eidx, counts);
    hipLaunchKernelGGL(csr_scan, dim3(1), dim3(256), 0, stream, counts, offsets, cursor);
    hipLaunchKernelGGL(csr_fill, dim3(EE / 256), dim3(256), 0, stream, eidx, cursor, perm);
    hipLaunchKernelGGL(edge_kernel, dim3(EE / TE, BB), dim3(256), 0, stream,
                       h, coord, eidx, perm, w1T, b1, w2T, b2, lng, lnb, cw1T, cb1, cw2,
                       efb, wd);
    hipLaunchKernelGGL(node_kernel, dim3(NN / NT, BB), dim3(256), 0, stream,
                       h, coord, efb, wd, offsets, nw1T, nb1, nw2T, nb2,
                       hout, coord_out);
}

// Round 7
// 345.775 us; speedup vs baseline: 3.2989x; 1.0492x over previous
//
#include <hip/hip_runtime.h>
#include <cstdint>
#include <cstddef>

#define BB 2
#define NN 8192
#define EE 131072
#define FFdim 128
#define HHdim 256
#define NHEAD 4
#define DHEAD 64
#define FEATD 268
#define K1PAD 288        // FEAT padded to multiple of 32
#define SF 296           // feat LDS row stride (ushort)
#define SH 264           // hmid/ef overlay stride (ushort); 528B, 16B-aligned
#define TE 64            // edges per edge-block
#define NT 32            // nodes per node-block
#define SA 392           // node A ([h|agg], 384) stride (ushort)
#define SM 264           // node mid overlay stride (ushort)

typedef short bf16x8 __attribute__((ext_vector_type(8)));
typedef float floatx4 __attribute__((ext_vector_type(4)));

__device__ __forceinline__ float silu_f(float x) {
    return x * __fdividef(1.0f, 1.0f + __expf(-x));
}
__device__ __forceinline__ unsigned short f2bf(float x) {
    unsigned int u = __float_as_uint(x);
    unsigned int r = (u + 0x7fffu + ((u >> 16) & 1u)) >> 16;
    return (unsigned short)r;
}
__device__ __forceinline__ float bf2f(unsigned short u) {
    return __uint_as_float(((unsigned int)u) << 16);
}
// permuted within-64 position p -> original offset (p = lm*4+ct, o = ct*16+lm)
__device__ __forceinline__ int operm(int p) { return ((p & 3) << 4) | (p >> 2); }

// ---------------------------------------------------------------------------
// prep: fp32 weights -> transposed (k-permuted) bf16; h -> bf16; zero counts.
#define W1T_ELEMS (256 * K1PAD)
#define W2T_ELEMS (256 * 64)
#define CW1T_ELEMS (256 * 256)
#define NW1T_ELEMS (256 * 384)
#define NW2T_ELEMS (128 * 256)
#define HBF_ELEMS (BB * NN * FFdim)
#define WT_A (W1T_ELEMS)
#define WT_B (W1T_ELEMS + W2T_ELEMS)
#define WT_C (W1T_ELEMS + W2T_ELEMS + CW1T_ELEMS)
#define WT_D (WT_C + NW1T_ELEMS)
#define WT_E (WT_D + NW2T_ELEMS)
#define WT_F (WT_E + NN)
#define WT_G (WT_F + HBF_ELEMS)
__global__ void prep_weights(const float* __restrict__ w1,
                             const float* __restrict__ w2,
                             const float* __restrict__ cw1,
                             const float* __restrict__ nw1,
                             const float* __restrict__ nw2,
                             const float* __restrict__ h,
                             unsigned short* __restrict__ w1T,
                             unsigned short* __restrict__ w2T,
                             unsigned short* __restrict__ cw1T,
                             unsigned short* __restrict__ nw1T,
                             unsigned short* __restrict__ nw2T,
                             unsigned short* __restrict__ hbf,
                             int* __restrict__ counts) {
    int idx = blockIdx.x * blockDim.x + threadIdx.x;
    if (idx < WT_A) {
        int n = idx / K1PAD, k = idx % K1PAD;
        int hh = n >> 6, d = n & 63;
        float v = (k < FEATD) ? w1[((size_t)hh * FEATD + k) * DHEAD + d] : 0.f;
        w1T[idx] = f2bf(v);
    } else if (idx < WT_B) {
        int j = idx - WT_A;
        int n = j >> 6, p = j & 63;
        int hh = n >> 6, dout = n & 63;
        int din = operm(p);
        w2T[j] = f2bf(w2[(size_t)hh * 4096 + din * 64 + dout]);
    } else if (idx < WT_C) {
        int j = idx - WT_B;
        int n = j >> 8, P = j & 255;
        int ko = (P >> 6) * 64 + operm(P & 63);
        cw1T[j] = f2bf(cw1[ko * 256 + n]);
    } else if (idx < WT_D) {
        int j = idx - WT_C;
        int n = j / 384, k = j % 384;
        int ko = (k < 128) ? k : 128 + ((k - 128) >> 6) * 64 + operm(k & 63);
        nw1T[j] = f2bf(nw1[ko * 256 + n]);
    } else if (idx < WT_E) {
        int j = idx - WT_D;
        int n = j >> 8, P = j & 255;
        int ko = (P >> 6) * 64 + operm(P & 63);
        nw2T[j] = f2bf(nw2[ko * 128 + n]);
    } else if (idx < WT_F) {
        counts[idx - WT_E] = 0;
    } else if (idx < WT_G) {
        int j = idx - WT_F;
        hbf[j] = f2bf(h[j]);
    }
}

// ---------------------------------------------------------------------------
// CSR build (row indices shared across batches)
__global__ void csr_count(const int* __restrict__ eidx, int* __restrict__ counts) {
    int e = blockIdx.x * 256 + threadIdx.x;
    atomicAdd(&counts[eidx[e]], 1);
}

__global__ void csr_scan(const int* __restrict__ counts,
                         int* __restrict__ offsets,
                         int* __restrict__ cursor) {
    __shared__ int wsum[4];
    const int t = threadIdx.x;
    const int base = t * 32;
    int local[32];
    int s = 0;
#pragma unroll
    for (int i = 0; i < 32; ++i) { local[i] = counts[base + i]; s += local[i]; }
    const int lane = t & 63, w = t >> 6;
    int v = s;
#pragma unroll
    for (int off = 1; off < 64; off <<= 1) {
        int u = __shfl_up(v, off, 64);
        if (lane >= off) v += u;
    }
    if (lane == 63) wsum[w] = v;
    __syncthreads();
    int wbase = 0;
    for (int i = 0; i < w; ++i) wbase += wsum[i];
    int run = wbase + v - s;
#pragma unroll
    for (int i = 0; i < 32; ++i) {
        offsets[base + i] = run;
        cursor[base + i] = run;
        run += local[i];
    }
    if (t == 255) offsets[NN] = run;
}

__global__ void csr_fill(const int* __restrict__ eidx,
                         int* __restrict__ cursor, int* __restrict__ perm) {
    int e = blockIdx.x * 256 + threadIdx.x;
    int r = eidx[e];
    int pos = atomicAdd(&cursor[r], 1);
    perm[e] = pos;
}

// ---------------------------------------------------------------------------
// edge kernel (MFMA bf16): one block = 64 edges of one batch, 256 threads.
// LDS trimmed to 40448B -> 4 blocks/CU. LN partials via LDS atomics.
__global__ __launch_bounds__(256, 4)
void edge_kernel(const unsigned short* __restrict__ hbf,
                 const float* __restrict__ coord,
                 const int* __restrict__ eidx,
                 const int* __restrict__ perm,
                 const unsigned short* __restrict__ w1T, const float* __restrict__ b1,
                 const unsigned short* __restrict__ w2T, const float* __restrict__ b2,
                 const float* __restrict__ lng, const float* __restrict__ lnb,
                 const unsigned short* __restrict__ cw1T, const float* __restrict__ cb1,
                 const float* __restrict__ cw2,
                 unsigned short* __restrict__ efb, float4* __restrict__ wd) {
    __shared__ unsigned short bufA[TE * SF];   // 37888B: feat; then hmid/ef (SH)
    __shared__ int slot_s[TE];                 // 256B
    __shared__ float cd_s[TE][3];              // 768B
    __shared__ float lns[TE], lns2[TE];        // 512B  (LN partial accumulators)
    __shared__ float scr[TE * 4];              // 1024B (mu|rs, later wpart)
    // total 40448B

    const int tid = threadIdx.x;
    const int b = blockIdx.y;
    const int e0 = blockIdx.x * TE;
    const int lane = tid & 63;
    const int w = tid >> 6;          // wave id = column quarter / head
    const int lm = lane & 15;
    const int quad = lane >> 4;
    const int koff = quad * 8;

    // --- phase 1: geometry + slot + LN-acc zero (one thread per edge) ---
    if (tid < TE) {
        lns[tid] = 0.f; lns2[tid] = 0.f;
        const int e = e0 + tid;
        const int r = eidx[e], c = eidx[EE + e];
        slot_s[tid] = perm[e];
        const float* pi = coord + ((size_t)b * NN + r) * 3;
        const float* pk = coord + ((size_t)b * NN + c) * 3;
        float ci0 = pi[0], ci1 = pi[1], ci2 = pi[2];
        float ck0 = pk[0], ck1 = pk[1], ck2 = pk[2];
        float dx = ci0 - ck0, dy = ci1 - ck1, dz = ci2 - ck2;
        float radial = dx * dx + dy * dy + dz * dz;
        float dist = sqrtf(radial);
        float dotv = ci0 * ck0 + ci1 * ck1 + ci2 * ck2;
        float inva = __fdividef(1.0f, dist + 1e-8f);
        float a0 = dx * inva, a1 = dy * inva, a2 = dz * inva;
        float cr0 = ci1 * ck2 - ci2 * ck1;
        float cr1 = ci2 * ck0 - ci0 * ck2;
        float cr2 = ci0 * ck1 - ci1 * ck0;
        float nb = sqrtf(cr0 * cr0 + cr1 * cr1 + cr2 * cr2);
        float invb = __fdividef(1.0f, nb + 1e-8f);
        float b0 = cr0 * invb, b1v = cr1 * invb, b2v = cr2 * invb;
        float c0 = a1 * b2v - a2 * b1v;
        float c1 = a2 * b0 - a0 * b2v;
        float c2 = a0 * b1v - a1 * b0;
        float na = sqrtf(a0 * a0 + a1 * a1 + a2 * a2);
        float nbn = sqrtf(b0 * b0 + b1v * b1v + b2v * b2v);
        float nc = sqrtf(c0 * c0 + c1 * c1 + c2 * c2);
        bool bad = (na < 1e-6f) || (nbn < 1e-6f) || (nc < 1e-6f);
        float s[12];
        s[0] = radial; s[1] = dist; s[2] = dotv;
        if (bad) {
            s[3] = 1.f; s[4] = 0.f; s[5] = 0.f;
            s[6] = 0.f; s[7] = 1.f; s[8] = 0.f;
            s[9] = 0.f; s[10] = 0.f; s[11] = 1.f;
        } else {
            s[3] = a0;  s[4] = b0;  s[5] = c0;
            s[6] = a1;  s[7] = b1v; s[8] = c1;
            s[9] = a2;  s[10] = b2v; s[11] = c2;
        }
        unsigned short* fp = &bufA[tid * SF];
#pragma unroll
        for (int q = 0; q < 12; ++q) fp[256 + q] = f2bf(s[q]);
#pragma unroll
        for (int q = FEATD; q < K1PAD; ++q) fp[q] = 0;
        cd_s[tid][0] = dx; cd_s[tid][1] = dy; cd_s[tid][2] = dz;
    }
    // --- phase 2: gather hbf[row] (cols 0..127) + hbf[col] (cols 128..255) ---
    // 32 chunks/edge x 8 bf16 = 256 values. (R6 bug: only 16 chunks -> NaN.)
    for (int idx = tid; idx < TE * 32; idx += 256) {
        const int e = idx >> 5, c16 = idx & 31;
        const int node = (c16 < 16) ? eidx[e0 + e] : eidx[EE + e0 + e];
        const int cc = (c16 & 15) * 8;
        uint4 v = *(const uint4*)&hbf[((size_t)b * NN + node) * FFdim + cc];
        *(uint4*)&bufA[e * SF + c16 * 8] = v;
    }
    __syncthreads();

    // --- GEMM1: feat[64 x 288] @ w1T -> hmid[64 x 256], silu ---
    floatx4 acc[4][4];
#pragma unroll
    for (int i = 0; i < 4; ++i)
#pragma unroll
        for (int j = 0; j < 4; ++j)
#pragma unroll
            for (int q = 0; q < 4; ++q) acc[i][j][q] = 0.f;
#pragma unroll
    for (int ks = 0; ks < K1PAD / 32; ++ks) {
        const int kb = ks * 32 + koff;
        bf16x8 a[4], bfr[4];
#pragma unroll
        for (int rt = 0; rt < 4; ++rt)
            a[rt] = *(const bf16x8*)&bufA[(rt * 16 + lm) * SF + kb];
#pragma unroll
        for (int ct = 0; ct < 4; ++ct)
            bfr[ct] = *(const bf16x8*)&w1T[(size_t)(w * 64 + ct * 16 + lm) * K1PAD + kb];
#pragma unroll
        for (int rt = 0; rt < 4; ++rt)
#pragma unroll
            for (int ct = 0; ct < 4; ++ct)
                acc[rt][ct] = __builtin_amdgcn_mfma_f32_16x16x32_bf16(
                    a[rt], bfr[ct], acc[rt][ct], 0, 0, 0);
    }
    float bias1[4];
#pragma unroll
    for (int ct = 0; ct < 4; ++ct) bias1[ct] = b1[w * 64 + ct * 16 + lm];
    __syncthreads();   // feat dead; bufA becomes hmid/ef (stride SH, pi-permuted)
#pragma unroll
    for (int rt = 0; rt < 4; ++rt)
#pragma unroll
        for (int reg = 0; reg < 4; ++reg) {
            const int row = rt * 16 + quad * 4 + reg;
            ushort4 pk;
            pk.x = f2bf(silu_f(acc[rt][0][reg] + bias1[0]));
            pk.y = f2bf(silu_f(acc[rt][1][reg] + bias1[1]));
            pk.z = f2bf(silu_f(acc[rt][2][reg] + bias1[2]));
            pk.w = f2bf(silu_f(acc[rt][3][reg] + bias1[3]));
            *(ushort4*)&bufA[row * SH + w * 64 + lm * 4] = pk;
        }
    // wave-local: wave w's GEMM2 reads only the quarter wave w wrote.

    // --- GEMM2: hmid[:, head w] @ w2T(head w) ---
    floatx4 acc2[4][4];
#pragma unroll
    for (int i = 0; i < 4; ++i)
#pragma unroll
        for (int j = 0; j < 4; ++j)
#pragma unroll
            for (int q = 0; q < 4; ++q) acc2[i][j][q] = 0.f;
#pragma unroll
    for (int ks = 0; ks < 2; ++ks) {
        const int kb = ks * 32 + koff;
        bf16x8 a[4], bfr[4];
#pragma unroll
        for (int rt = 0; rt < 4; ++rt)
            a[rt] = *(const bf16x8*)&bufA[(rt * 16 + lm) * SH + w * 64 + kb];
#pragma unroll
        for (int ct = 0; ct < 4; ++ct)
            bfr[ct] = *(const bf16x8*)&w2T[(size_t)(w * 64 + ct * 16 + lm) * 64 + kb];
#pragma unroll
        for (int rt = 0; rt < 4; ++rt)
#pragma unroll
            for (int ct = 0; ct < 4; ++ct)
                acc2[rt][ct] = __builtin_amdgcn_mfma_f32_16x16x32_bf16(
                    a[rt], bfr[ct], acc2[rt][ct], 0, 0, 0);
    }
    // --- bias + LN partials via LDS atomics ---
    float bias2[4];
#pragma unroll
    for (int ct = 0; ct < 4; ++ct) bias2[ct] = b2[w * 64 + ct * 16 + lm];
#pragma unroll
    for (int rt = 0; rt < 4; ++rt)
#pragma unroll
        for (int reg = 0; reg < 4; ++reg) {
            float s = 0.f, s2 = 0.f;
#pragma unroll
            for (int ct = 0; ct < 4; ++ct) {
                float v = acc2[rt][ct][reg] + bias2[ct];
                acc2[rt][ct][reg] = v;
                s += v; s2 += v * v;
            }
#pragma unroll
            for (int m = 1; m <= 8; m <<= 1) {
                s += __shfl_xor(s, m, 64);
                s2 += __shfl_xor(s2, m, 64);
            }
            if (lm == 0) {
                const int row = rt * 16 + quad * 4 + reg;
                atomicAdd(&lns[row], s);
                atomicAdd(&lns2[row], s2);
            }
        }
    __syncthreads();
    if (tid < TE) {
        float mean = lns[tid] * (1.0f / 256.0f);
        float var = lns2[tid] * (1.0f / 256.0f) - mean * mean;
        scr[tid] = mean;                       // mu
        scr[TE + tid] = rsqrtf(var + 1e-5f);   // rs
    }
    __syncthreads();
    {
        float gv[4], bv[4];
#pragma unroll
        for (int ct = 0; ct < 4; ++ct) {
            const int col = w * 64 + ct * 16 + lm;
            gv[ct] = lng[col]; bv[ct] = lnb[col];
        }
#pragma unroll
        for (int rt = 0; rt < 4; ++rt)
#pragma unroll
            for (int reg = 0; reg < 4; ++reg) {
                const int row = rt * 16 + quad * 4 + reg;
                const float mu = scr[row], rs = scr[TE + row];
                ushort4 pk;
                pk.x = f2bf((acc2[rt][0][reg] - mu) * rs * gv[0] + bv[0]);
                pk.y = f2bf((acc2[rt][1][reg] - mu) * rs * gv[1] + bv[1]);
                pk.z = f2bf((acc2[rt][2][reg] - mu) * rs * gv[2] + bv[2]);
                pk.w = f2bf((acc2[rt][3][reg] - mu) * rs * gv[3] + bv[3]);
                *(ushort4*)&bufA[row * SH + w * 64 + lm * 4] = pk;
            }
    }
    __syncthreads();   // all mu/rs reads done -> scr reusable as wpart

    // --- GEMM3: ef[64 x 256] @ cw1T -> silu -> dot cw2 -> w per edge ---
    floatx4 acc3[4][4];
#pragma unroll
    for (int i = 0; i < 4; ++i)
#pragma unroll
        for (int j = 0; j < 4; ++j)
#pragma unroll
            for (int q = 0; q < 4; ++q) acc3[i][j][q] = 0.f;
#pragma unroll
    for (int ks = 0; ks < 8; ++ks) {
        const int kb = ks * 32 + koff;
        bf16x8 a[4], bfr[4];
#pragma unroll
        for (int rt = 0; rt < 4; ++rt)
            a[rt] = *(const bf16x8*)&bufA[(rt * 16 + lm) * SH + kb];
#pragma unroll
        for (int ct = 0; ct < 4; ++ct)
            bfr[ct] = *(const bf16x8*)&cw1T[(size_t)(w * 64 + ct * 16 + lm) * 256 + kb];
#pragma unroll
        for (int rt = 0; rt < 4; ++rt)
#pragma unroll
            for (int ct = 0; ct < 4; ++ct)
                acc3[rt][ct] = __builtin_amdgcn_mfma_f32_16x16x32_bf16(
                    a[rt], bfr[ct], acc3[rt][ct], 0, 0, 0);
    }
    {
        float cb[4], cwv[4];
#pragma unroll
        for (int ct = 0; ct < 4; ++ct) {
            const int col = w * 64 + ct * 16 + lm;
            cb[ct] = cb1[col]; cwv[ct] = cw2[col];
        }
#pragma unroll
        for (int rt = 0; rt < 4; ++rt)
#pragma unroll
            for (int reg = 0; reg < 4; ++reg) {
                float s = 0.f;
#pragma unroll
                for (int ct = 0; ct < 4; ++ct)
                    s += silu_f(acc3[rt][ct][reg] + cb[ct]) * cwv[ct];
#pragma unroll
                for (int m = 1; m <= 8; m <<= 1) s += __shfl_xor(s, m, 64);
                if (lm == 0) scr[(rt * 16 + quad * 4 + reg) * 4 + w] = s;  // wpart
            }
    }
    __syncthreads();

    // --- streaming outputs to CSR slots ---
    if (tid < TE) {
        float ww = scr[tid * 4] + scr[tid * 4 + 1] + scr[tid * 4 + 2] + scr[tid * 4 + 3];
        float4 o = { cd_s[tid][0] * ww, cd_s[tid][1] * ww, cd_s[tid][2] * ww, 0.f };
        wd[(size_t)b * EE + slot_s[tid]] = o;
    }
    for (int idx = tid; idx < TE * 32; idx += 256) {   // 32 x 16B per row
        const int e = idx >> 5, c = idx & 31;
        uint4 v = *(const uint4*)&bufA[e * SH + c * 8];
        *(uint4*)&efb[((size_t)b * EE + slot_s[e]) * HHdim + c * 8] = v;
    }
}

// ---------------------------------------------------------------------------
// fused gather + node MLP (MFMA bf16): one block = 32 nodes of one batch.
__global__ __launch_bounds__(256, 4)
void node_kernel(const float* __restrict__ h,
                 const unsigned short* __restrict__ hbf,
                 const float* __restrict__ coord,
                 const unsigned short* __restrict__ efb,
                 const float4* __restrict__ wd,
                 const int* __restrict__ offsets,
                 const unsigned short* __restrict__ nw1T, const float* __restrict__ nb1,
                 const unsigned short* __restrict__ nw2T, const float* __restrict__ nb2,
                 float* __restrict__ hout, float* __restrict__ coord_out) {
    __shared__ unsigned short bufN[NT * SA];   // [h|agg] bf16; then mid overlay (SM)

    const int tid = threadIdx.x;
    const int b = blockIdx.y;
    const int n0 = blockIdx.x * NT;
    const int lane = tid & 63;
    const int w = tid >> 6;
    const int lm = lane & 15;
    const int quad = lane >> 4;
    const int koff = quad * 8;

    // stage hbf rows (pure uint4 copies), cols 0..127
    for (int idx = tid; idx < NT * 16; idx += 256) {
        const int r = idx >> 4, c8 = idx & 15;
        uint4 v = *(const uint4*)&hbf[((size_t)b * NN + n0 + r) * FFdim + c8 * 8];
        *(uint4*)&bufN[r * SA + c8 * 8] = v;
    }

    // gather: wave w handles nodes w*8 .. w*8+7 (slot ranges contiguous)
    for (int i = 0; i < 8; ++i) {
        const int r = w * 8 + i;
        const int n = n0 + r;
        const int o0 = offsets[n], o1 = offsets[n + 1];
        float a0 = 0.f, a1 = 0.f, a2 = 0.f, a3 = 0.f;
        const unsigned short* ebase = efb + (size_t)b * EE * HHdim + lane * 4;
        int j = o0;
        for (; j + 4 <= o1; j += 4) {
            ushort4 u0 = *(const ushort4*)(ebase + (size_t)(j + 0) * HHdim);
            ushort4 u1 = *(const ushort4*)(ebase + (size_t)(j + 1) * HHdim);
            ushort4 u2 = *(const ushort4*)(ebase + (size_t)(j + 2) * HHdim);
            ushort4 u3 = *(const ushort4*)(ebase + (size_t)(j + 3) * HHdim);
            a0 += bf2f(u0.x) + bf2f(u1.x) + bf2f(u2.x) + bf2f(u3.x);
            a1 += bf2f(u0.y) + bf2f(u1.y) + bf2f(u2.y) + bf2f(u3.y);
            a2 += bf2f(u0.z) + bf2f(u1.z) + bf2f(u2.z) + bf2f(u3.z);
            a3 += bf2f(u0.w) + bf2f(u1.w) + bf2f(u2.w) + bf2f(u3.w);
        }
        for (; j < o1; ++j) {
            ushort4 u = *(const ushort4*)(ebase + (size_t)j * HHdim);
            a0 += bf2f(u.x); a1 += bf2f(u.y); a2 += bf2f(u.z); a3 += bf2f(u.w);
        }
        ushort4 o;
        o.x = f2bf(a0); o.y = f2bf(a1); o.z = f2bf(a2); o.w = f2bf(a3);
        *(ushort4*)&bufN[r * SA + FFdim + lane * 4] = o;

        // coord_out = coord + sum(wd)
        float sx = 0.f, sy = 0.f, sz = 0.f;
        for (int jj = o0 + lane; jj < o1; jj += 64) {
            float4 t = wd[(size_t)b * EE + jj];
            sx += t.x; sy += t.y; sz += t.z;
        }
#pragma unroll
        for (int m = 1; m < 64; m <<= 1) {
            sx += __shfl_xor(sx, m, 64);
            sy += __shfl_xor(sy, m, 64);
            sz += __shfl_xor(sz, m, 64);
        }
        if (lane < 3) {
            const size_t cb = ((size_t)b * NN + n) * 3 + lane;
            float s = (lane == 0) ? sx : (lane == 1) ? sy : sz;
            coord_out[cb] = coord[cb] + s;
        }
    }
    __syncthreads();

    // GEMM-A: [h|agg][32 x 384] @ nw1T -> mid[32 x 256], silu (pi-packed store)
    floatx4 acc[2][4];
#pragma unroll
    for (int i = 0; i < 2; ++i)
#pragma unroll
        for (int j = 0; j < 4; ++j)
#pragma unroll
            for (int q = 0; q < 4; ++q) acc[i][j][q] = 0.f;
#pragma unroll
    for (int ks = 0; ks < 12; ++ks) {
        const int kb = ks * 32 + koff;
        bf16x8 a[2], bfr[4];
#pragma unroll
        for (int rt = 0; rt < 2; ++rt)
            a[rt] = *(const bf16x8*)&bufN[(rt * 16 + lm) * SA + kb];
#pragma unroll
        for (int ct = 0; ct < 4; ++ct)
            bfr[ct] = *(const bf16x8*)&nw1T[(size_t)(w * 64 + ct * 16 + lm) * 384 + kb];
#pragma unroll
        for (int rt = 0; rt < 2; ++rt)
#pragma unroll
            for (int ct = 0; ct < 4; ++ct)
                acc[rt][ct] = __builtin_amdgcn_mfma_f32_16x16x32_bf16(
                    a[rt], bfr[ct], acc[rt][ct], 0, 0, 0);
    }
    float nb1v[4];
#pragma unroll
    for (int ct = 0; ct < 4; ++ct) nb1v[ct] = nb1[w * 64 + ct * 16 + lm];
    __syncthreads();   // A dead; overlay mid (stride SM, pi-permuted)
#pragma unroll
    for (int rt = 0; rt < 2; ++rt)
#pragma unroll
        for (int reg = 0; reg < 4; ++reg) {
            const int row = rt * 16 + quad * 4 + reg;
            ushort4 pk;
            pk.x = f2bf(silu_f(acc[rt][0][reg] + nb1v[0]));
            pk.y = f2bf(silu_f(acc[rt][1][reg] + nb1v[1]));
            pk.z = f2bf(silu_f(acc[rt][2][reg] + nb1v[2]));
            pk.w = f2bf(silu_f(acc[rt][3][reg] + nb1v[3]));
            *(ushort4*)&bufN[row * SM + w * 64 + lm * 4] = pk;
        }
    __syncthreads();

    // GEMM-B: mid[32 x 256] @ nw2T -> out[32 x 128] + bias + residual
    floatx4 accb[2][2];
#pragma unroll
    for (int i = 0; i < 2; ++i)
#pragma unroll
        for (int j = 0; j < 2; ++j)
#pragma unroll
            for (int q = 0; q < 4; ++q) accb[i][j][q] = 0.f;
#pragma unroll
    for (int ks = 0; ks < 8; ++ks) {
        const int kb = ks * 32 + koff;
        bf16x8 a[2], bfr[2];
#pragma unroll
        for (int rt = 0; rt < 2; ++rt)
            a[rt] = *(const bf16x8*)&bufN[(rt * 16 + lm) * SM + kb];
#pragma unroll
        for (int ct = 0; ct < 2; ++ct)
            bfr[ct] = *(const bf16x8*)&nw2T[(size_t)(w * 32 + ct * 16 + lm) * 256 + kb];
#pragma unroll
        for (int rt = 0; rt < 2; ++rt)
#pragma unroll
            for (int ct = 0; ct < 2; ++ct)
                accb[rt][ct] = __builtin_amdgcn_mfma_f32_16x16x32_bf16(
                    a[rt], bfr[ct], accb[rt][ct], 0, 0, 0);
    }
#pragma unroll
    for (int ct = 0; ct < 2; ++ct) {
        const int col = w * 32 + ct * 16 + lm;
        const float bias = nb2[col];
#pragma unroll
        for (int rt = 0; rt < 2; ++rt)
#pragma unroll
            for (int reg = 0; reg < 4; ++reg) {
                const int row = rt * 16 + quad * 4 + reg;
                const size_t gi = ((size_t)b * NN + n0 + row) * FFdim + col;
                hout[gi] = accb[rt][ct][reg] + bias + h[gi];
            }
    }
}

// ---------------------------------------------------------------------------
extern "C" void kernel_launch(void* const* d_in, const int* in_sizes, int n_in,
                              void* d_out, int out_size, void* d_ws, size_t ws_size,
                              hipStream_t stream) {
    const float* h     = (const float*)d_in[0];
    const float* coord = (const float*)d_in[1];
    const int*   eidx  = (const int*)d_in[2];
    const float* w1    = (const float*)d_in[3];
    const float* b1    = (const float*)d_in[4];
    const float* w2    = (const float*)d_in[5];
    const float* b2    = (const float*)d_in[6];
    const float* lng   = (const float*)d_in[7];
    const float* lnb   = (const float*)d_in[8];
    const float* nw1   = (const float*)d_in[9];
    const float* nb1   = (const float*)d_in[10];
    const float* nw2   = (const float*)d_in[11];
    const float* nb2   = (const float*)d_in[12];
    const float* cw1   = (const float*)d_in[13];
    const float* cb1   = (const float*)d_in[14];
    const float* cw2   = (const float*)d_in[15];

    float* hout = (float*)d_out;
    float* coord_out = hout + (size_t)BB * NN * FFdim;

    char* p = (char*)d_ws;
    float4* wd = (float4*)p;                   p += (size_t)BB * EE * 16;          // 4 MB
    unsigned short* efb = (unsigned short*)p;  p += (size_t)BB * EE * HHdim * 2;   // 134 MB
    unsigned short* hbf = (unsigned short*)p;  p += (size_t)HBF_ELEMS * 2;         // 4 MB
    unsigned short* w1T = (unsigned short*)p;  p += (size_t)W1T_ELEMS * 2;
    unsigned short* w2T = (unsigned short*)p;  p += (size_t)W2T_ELEMS * 2;
    unsigned short* cw1T = (unsigned short*)p; p += (size_t)CW1T_ELEMS * 2;
    unsigned short* nw1T = (unsigned short*)p; p += (size_t)NW1T_ELEMS * 2;
    unsigned short* nw2T = (unsigned short*)p; p += (size_t)NW2T_ELEMS * 2;
    int* counts = (int*)p;                     p += (size_t)NN * 4;
    int* offsets = (int*)p;                    p += (size_t)(NN + 1) * 4;
    int* cursor = (int*)p;                     p += (size_t)NN * 4;
    int* perm = (int*)p;                       p += (size_t)EE * 4;

    hipLaunchKernelGGL(prep_weights, dim3((WT_G + 255) / 256), dim3(256),
                       0, stream, w1, w2, cw1, nw1, nw2, h,
                       w1T, w2T, cw1T, nw1T, nw2T, hbf, counts);
    hipLaunchKernelGGL(csr_count, dim3(EE / 256), dim3(256), 0, stream, eidx, counts);
    hipLaunchKernelGGL(csr_scan, dim3(1), dim3(256), 0, stream, counts, offsets, cursor);
    hipLaunchKernelGGL(csr_fill, dim3(EE / 256), dim3(256), 0, stream, eidx, cursor, perm);
    hipLaunchKernelGGL(edge_kernel, dim3(EE / TE, BB), dim3(256), 0, stream,
                       hbf, coord, eidx, perm, w1T, b1, w2T, b2, lng, lnb, cw1T, cb1, cw2,
                       efb, wd);
    hipLaunchKernelGGL(node_kernel, dim3(NN / NT, BB), dim3(256), 0, stream,
                       h, hbf, coord, efb, wd, offsets, nw1T, nb1, nw2T, nb2,
                       hout, coord_out);
}